// Round 4
// baseline (1644.790 us; speedup 1.0000x reference)
//
#include <hip/hip_runtime.h>

#define NN 100000
#define NE 2500000
#define NB_SCAN ((NN + 255) / 256)          // 391 scan blocks
#define BK_SHIFT 7
#define BK_NODES 128
#define NBUCK ((NN + BK_NODES - 1) / BK_NODES)   // 782
#define NBUCK_PAD 1024
#define TILE 4096
#define NTILES ((NE + TILE - 1) / TILE)     // 611
#define SRC_MASK 0x1FFFF                    // 17 bits, NN < 131072

// ---------------- degree histogram ----------------

__global__ void k_hist(const int* __restrict__ src, const int* __restrict__ dst,
                       int* __restrict__ cnt_out, int* __restrict__ cnt_in, int E) {
    int i = blockIdx.x * blockDim.x + threadIdx.x;
    if (i < E) {
        atomicAdd(&cnt_out[src[i]], 1);
        atomicAdd(&cnt_in[dst[i]], 1);
    }
}

// ---------------- row_ptr scan (per node; bucket offsets = rp[b*128]) ----------------

__global__ void k_scan_blocks(const int* __restrict__ cnt, int* __restrict__ row_ptr,
                              int* __restrict__ bsum, int N) {
    __shared__ int sh[256];
    int i = blockIdx.x * 256 + threadIdx.x;
    int v = (i < N) ? cnt[i] : 0;
    sh[threadIdx.x] = v;
    __syncthreads();
#pragma unroll
    for (int off = 1; off < 256; off <<= 1) {
        int t = (threadIdx.x >= off) ? sh[threadIdx.x - off] : 0;
        __syncthreads();
        sh[threadIdx.x] += t;
        __syncthreads();
    }
    if (i < N) row_ptr[i] = sh[threadIdx.x] - v;  // exclusive, pre-offset
    if (threadIdx.x == 255) bsum[blockIdx.x] = sh[255];
}

__global__ void k_scan_top(const int* __restrict__ bsum, int* __restrict__ bsum_ex, int NB) {
    __shared__ int sh[512];
    int tid = threadIdx.x;
    int v = (tid < NB) ? bsum[tid] : 0;
    sh[tid] = v;
    __syncthreads();
#pragma unroll
    for (int off = 1; off < 512; off <<= 1) {
        int t = (tid >= off) ? sh[tid - off] : 0;
        __syncthreads();
        sh[tid] += t;
        __syncthreads();
    }
    if (tid < NB) bsum_ex[tid] = sh[tid] - v;
}

// add block offsets; init per-bucket cursor; row_ptr[N]=E; fused prep:
// norms from degrees + xs[n*8+f] = x[n*7+f]*norm_out (8-padded)
__global__ void k_scan_add_prep(int* __restrict__ row_ptr, const int* __restrict__ bsum_ex,
                                int* __restrict__ cursor, const int* __restrict__ cnt_out,
                                const int* __restrict__ cnt_in, const float* __restrict__ x,
                                float* __restrict__ no, float* __restrict__ ni,
                                float* __restrict__ xs, int N, int E) {
    int i = blockIdx.x * blockDim.x + threadIdx.x;
    if (i < N) {
        int r = row_ptr[i] + bsum_ex[i >> 8];
        row_ptr[i] = r;
        if ((i & (BK_NODES - 1)) == 0) cursor[i >> BK_SHIFT] = r;
        float nov = rsqrtf(fmaxf((float)cnt_out[i], 1.0f));
        float niv = rsqrtf(fmaxf((float)cnt_in[i], 1.0f));
        no[i] = nov;
        ni[i] = niv;
#pragma unroll
        for (int f = 0; f < 7; ++f) xs[i * 8 + f] = x[i * 7 + f] * nov;
        xs[i * 8 + 7] = 0.f;
    } else if (i == N) {
        row_ptr[N] = E;
    }
}

// ---------------- bucket-binning pass (replaces random scatter) ----------------
// bin_sw[pos] = src | (dst_local << 17);  bin_w[pos] = edge_weight
__global__ __launch_bounds__(256) void k_binpass(
    const int* __restrict__ src, const int* __restrict__ dst, const float* __restrict__ ew,
    int* __restrict__ cursor, int* __restrict__ bin_sw, float* __restrict__ bin_w, int E) {
    __shared__ int cnt[NBUCK_PAD];
    __shared__ int offs[NBUCK_PAD];
    __shared__ int gpos[NBUCK_PAD];
    __shared__ int sc[256];
    __shared__ int st0[TILE];
    __shared__ float st1[TILE];
    __shared__ unsigned short stb[TILE];

    int base = blockIdx.x * TILE;
    int tn = E - base; if (tn > TILE) tn = TILE;

    for (int i = threadIdx.x; i < NBUCK_PAD; i += 256) cnt[i] = 0;
    __syncthreads();

    int myw0[16]; float myw1[16]; int myb[16]; int myr[16];
#pragma unroll
    for (int k = 0; k < 16; ++k) {
        int idx = base + threadIdx.x + k * 256;
        myb[k] = -1;
        if (idx < E) {
            int s = src[idx], d = dst[idx];
            myw1[k] = ew[idx];
            int b = d >> BK_SHIFT;
            myw0[k] = s | ((d & (BK_NODES - 1)) << 17);
            myb[k] = b;
            myr[k] = atomicAdd(&cnt[b], 1);
        }
    }
    __syncthreads();

    // block scan of cnt[0..NBUCK) : 4 buckets per thread
    int t = threadIdx.x;
    int c0 = cnt[t * 4], c1 = cnt[t * 4 + 1], c2 = cnt[t * 4 + 2], c3 = cnt[t * 4 + 3];
    int tot = c0 + c1 + c2 + c3;
    sc[t] = tot;
    __syncthreads();
#pragma unroll
    for (int off = 1; off < 256; off <<= 1) {
        int v = (t >= off) ? sc[t - off] : 0;
        __syncthreads();
        sc[t] += v;
        __syncthreads();
    }
    int run = sc[t] - tot;
    {
        int b = t * 4;
        offs[b] = run;
        if (c0 > 0) gpos[b] = atomicAdd(&cursor[b], c0);
        run += c0;
        offs[b + 1] = run;
        if (c1 > 0) gpos[b + 1] = atomicAdd(&cursor[b + 1], c1);
        run += c1;
        offs[b + 2] = run;
        if (c2 > 0) gpos[b + 2] = atomicAdd(&cursor[b + 2], c2);
        run += c2;
        offs[b + 3] = run;
        if (c3 > 0) gpos[b + 3] = atomicAdd(&cursor[b + 3], c3);
    }
    __syncthreads();

    // stage into LDS grouped by bucket
#pragma unroll
    for (int k = 0; k < 16; ++k) {
        if (myb[k] >= 0) {
            int p = offs[myb[k]] + myr[k];
            st0[p] = myw0[k];
            st1[p] = myw1[k];
            stb[p] = (unsigned short)myb[k];
        }
    }
    __syncthreads();

    // flush: contiguous runs per bucket -> per-bucket global regions
    for (int i = threadIdx.x; i < tn; i += 256) {
        int b = stb[i];
        int dest = gpos[b] + (i - offs[b]);
        bin_sw[dest] = st0[i];
        bin_w[dest] = st1[i];
    }
}

// ---------------- fused layers: LDS-accumulated bucket aggregation ----------------

// layer 1 (7-wide weighted): 8 lanes/edge
__global__ __launch_bounds__(256) void k_layer1(
    const int* __restrict__ rp, const int* __restrict__ bin_sw, const float* __restrict__ bin_w,
    const float* __restrict__ xs, const float* __restrict__ ni, const float* __restrict__ no,
    const float* __restrict__ W1, const float* __restrict__ b1, float* __restrict__ h1s, int N) {
    __shared__ float sW[7 * 32];
    __shared__ float sb[32];
    __shared__ float acc[BK_NODES][8];
    int b = blockIdx.x;
    int beg = rp[b << BK_SHIFT];
    int endn = (b + 1) << BK_SHIFT; if (endn > N) endn = N;
    int end = rp[endn];
    for (int i = threadIdx.x; i < 7 * 32; i += 256) sW[i] = W1[i];
    if (threadIdx.x < 32) sb[threadIdx.x] = b1[threadIdx.x];
    for (int i = threadIdx.x; i < BK_NODES * 8; i += 256) ((float*)acc)[i] = 0.f;
    __syncthreads();

    int g = threadIdx.x >> 3, lane = threadIdx.x & 7;  // 32 groups of 8
    int e = beg + g;
    for (; e + 32 < end; e += 64) {
        int w0a = bin_sw[e];       float wa = bin_w[e];
        int w0b = bin_sw[e + 32];  float wb = bin_w[e + 32];
        float va = xs[(w0a & SRC_MASK) * 8 + lane] * wa;
        float vb = xs[(w0b & SRC_MASK) * 8 + lane] * wb;
        atomicAdd(&acc[w0a >> 17][lane], va);
        atomicAdd(&acc[w0b >> 17][lane], vb);
    }
    if (e < end) {
        int w0 = bin_sw[e];
        float w = bin_w[e];
        float v = xs[(w0 & SRC_MASK) * 8 + lane] * w;
        atomicAdd(&acc[w0 >> 17][lane], v);
    }
    __syncthreads();

    int l32 = threadIdx.x & 31, r = threadIdx.x >> 5;
    for (int i = r; i < BK_NODES; i += 8) {
        int n = (b << BK_SHIFT) + i;
        if (n < N) {
            float o = 0.f;
#pragma unroll
            for (int k = 0; k < 7; ++k) o += acc[i][k] * sW[k * 32 + l32];
            o = o * ni[n] + sb[l32];
            h1s[n * 32 + l32] = fmaxf(o, 0.f) * no[n];
        }
    }
}

// 32-wide layer: 32 lanes/edge, unroll x2, fused 32x32 matmul epilogue
__global__ __launch_bounds__(512) void k_layer32(
    const int* __restrict__ rp, const int* __restrict__ bin_sw, const float* __restrict__ h_in,
    const float* __restrict__ ni, const float* __restrict__ no, const float* __restrict__ W,
    const float* __restrict__ bia, float* __restrict__ h_out, int N) {
    __shared__ float sW[32 * 32];
    __shared__ float sb[32];
    __shared__ float acc[BK_NODES][32];
    int b = blockIdx.x;
    int beg = rp[b << BK_SHIFT];
    int endn = (b + 1) << BK_SHIFT; if (endn > N) endn = N;
    int end = rp[endn];
    for (int i = threadIdx.x; i < 1024; i += 512) sW[i] = W[i];
    if (threadIdx.x < 32) sb[threadIdx.x] = bia[threadIdx.x];
    for (int i = threadIdx.x; i < BK_NODES * 32; i += 512) ((float*)acc)[i] = 0.f;
    __syncthreads();

    int g = threadIdx.x >> 5, lane = threadIdx.x & 31;  // 16 groups of 32
    int e = beg + g;
    for (; e + 16 < end; e += 32) {
        int w0 = bin_sw[e];
        int w1 = bin_sw[e + 16];
        float v0 = h_in[(w0 & SRC_MASK) * 32 + lane];
        float v1 = h_in[(w1 & SRC_MASK) * 32 + lane];
        atomicAdd(&acc[w0 >> 17][lane], v0);
        atomicAdd(&acc[w1 >> 17][lane], v1);
    }
    if (e < end) {
        int w0 = bin_sw[e];
        float v0 = h_in[(w0 & SRC_MASK) * 32 + lane];
        atomicAdd(&acc[w0 >> 17][lane], v0);
    }
    __syncthreads();

    int r = threadIdx.x >> 5;
    for (int i = r; i < BK_NODES; i += 16) {
        int n = (b << BK_SHIFT) + i;
        if (n < N) {
            float o = 0.f;
#pragma unroll
            for (int k = 0; k < 32; ++k) o += acc[i][k] * sW[k * 32 + lane];
            o = o * ni[n] + sb[lane];
            h_out[n * 32 + lane] = fmaxf(o, 0.f) * no[n];
        }
    }
}

// layer 3 + W4 pre-multiply epilogue: h4pre[n] = (relu(ni*(acc@W3)+b3)*no) @ W4
__global__ __launch_bounds__(512) void k_layer34(
    const int* __restrict__ rp, const int* __restrict__ bin_sw, const float* __restrict__ h_in,
    const float* __restrict__ ni, const float* __restrict__ no, const float* __restrict__ W3,
    const float* __restrict__ b3, const float* __restrict__ W4, float2* __restrict__ h4pre, int N) {
    __shared__ float sW[32 * 32];
    __shared__ float sb[32];
    __shared__ float sW4[64];
    __shared__ float acc[BK_NODES][32];
    int b = blockIdx.x;
    int beg = rp[b << BK_SHIFT];
    int endn = (b + 1) << BK_SHIFT; if (endn > N) endn = N;
    int end = rp[endn];
    for (int i = threadIdx.x; i < 1024; i += 512) sW[i] = W3[i];
    if (threadIdx.x < 32) sb[threadIdx.x] = b3[threadIdx.x];
    if (threadIdx.x < 64) sW4[threadIdx.x] = W4[threadIdx.x];
    for (int i = threadIdx.x; i < BK_NODES * 32; i += 512) ((float*)acc)[i] = 0.f;
    __syncthreads();

    int g = threadIdx.x >> 5, lane = threadIdx.x & 31;
    int e = beg + g;
    for (; e + 16 < end; e += 32) {
        int w0 = bin_sw[e];
        int w1 = bin_sw[e + 16];
        float v0 = h_in[(w0 & SRC_MASK) * 32 + lane];
        float v1 = h_in[(w1 & SRC_MASK) * 32 + lane];
        atomicAdd(&acc[w0 >> 17][lane], v0);
        atomicAdd(&acc[w1 >> 17][lane], v1);
    }
    if (e < end) {
        int w0 = bin_sw[e];
        float v0 = h_in[(w0 & SRC_MASK) * 32 + lane];
        atomicAdd(&acc[w0 >> 17][lane], v0);
    }
    __syncthreads();

    int r = threadIdx.x >> 5;
    for (int i = r; i < BK_NODES; i += 16) {
        int n = (b << BK_SHIFT) + i;
        if (n < N) {
            float o = 0.f;
#pragma unroll
            for (int k = 0; k < 32; ++k) o += acc[i][k] * sW[k * 32 + lane];
            o = o * ni[n] + sb[lane];
            float tv = fmaxf(o, 0.f) * no[n];
            float px = tv * sW4[lane * 2 + 0];
            float py = tv * sW4[lane * 2 + 1];
#pragma unroll
            for (int off = 16; off; off >>= 1) {
                px += __shfl_xor(px, off, 32);
                py += __shfl_xor(py, off, 32);
            }
            if (lane == 0) h4pre[n] = make_float2(px, py);
        }
    }
}

// layer-4 aggregation (2-dim), bucket LDS accumulate; stores agg*ni
__global__ __launch_bounds__(256) void k_agg4(
    const int* __restrict__ rp, const int* __restrict__ bin_sw, const float2* __restrict__ h4pre,
    const float* __restrict__ ni, float2* __restrict__ agg2, int N) {
    __shared__ float acc2[BK_NODES][2];
    int b = blockIdx.x;
    int beg = rp[b << BK_SHIFT];
    int endn = (b + 1) << BK_SHIFT; if (endn > N) endn = N;
    int end = rp[endn];
    for (int i = threadIdx.x; i < BK_NODES * 2; i += 256) ((float*)acc2)[i] = 0.f;
    __syncthreads();
    for (int e = beg + threadIdx.x; e < end; e += 256) {
        int w0 = bin_sw[e];
        float2 v = h4pre[w0 & SRC_MASK];
        int dl = w0 >> 17;
        atomicAdd(&acc2[dl][0], v.x);
        atomicAdd(&acc2[dl][1], v.y);
    }
    __syncthreads();
    int i = threadIdx.x;
    if (i < BK_NODES) {
        int n = (b << BK_SHIFT) + i;
        if (n < N) {
            float w = ni[n];
            agg2[n] = make_float2(acc2[i][0] * w, acc2[i][1] * w);
        }
    }
}

// mean pooling: gid sorted -> one wave/graph, binary-search range
__global__ void k_pool(const float2* __restrict__ agg2, const int* __restrict__ gid,
                       const float* __restrict__ b4, float* __restrict__ out, int N) {
    int g = blockIdx.x;
    int lo = 0, hi = N;
    while (lo < hi) { int m = (lo + hi) >> 1; if (gid[m] < g) lo = m + 1; else hi = m; }
    int start = lo;
    int lo2 = start, hi2 = N;
    while (lo2 < hi2) { int m = (lo2 + hi2) >> 1; if (gid[m] < g + 1) lo2 = m + 1; else hi2 = m; }
    int end = lo2;
    float sx = 0.f, sy = 0.f;
    for (int n = start + threadIdx.x; n < end; n += 64) {
        float2 v = agg2[n];
        sx += v.x;
        sy += v.y;
    }
#pragma unroll
    for (int off = 32; off; off >>= 1) {
        sx += __shfl_down(sx, off, 64);
        sy += __shfl_down(sy, off, 64);
    }
    if (threadIdx.x == 0) {
        int cnt = end - start;
        float inv = 1.0f / fmaxf((float)cnt, 1.0f);
        float scale = (float)cnt * inv;  // 0 if empty, else 1
        out[g * 2 + 0] = sx * inv + b4[0] * scale;
        out[g * 2 + 1] = sy * inv + b4[1] * scale;
    }
}

// ---------------- launch ----------------

extern "C" void kernel_launch(void* const* d_in, const int* in_sizes, int n_in,
                              void* d_out, int out_size, void* d_ws, size_t ws_size,
                              hipStream_t stream) {
    const float* x   = (const float*)d_in[0];
    const float* e   = (const float*)d_in[1];
    const float* W1  = (const float*)d_in[2];
    const float* b1  = (const float*)d_in[3];
    const float* W2  = (const float*)d_in[4];
    const float* b2  = (const float*)d_in[5];
    const float* W3  = (const float*)d_in[6];
    const float* b3  = (const float*)d_in[7];
    const float* W4  = (const float*)d_in[8];
    const float* b4  = (const float*)d_in[9];
    const int*   src = (const int*)d_in[10];
    const int*   dst = (const int*)d_in[11];
    const int*   gid = (const int*)d_in[12];
    float* out = (float*)d_out;

    const int N = NN, E = NE;
    const int G = out_size / 2;

    int* ws_i = (int*)d_ws;
    int* cnt_out = ws_i;                          // N
    int* cnt_in  = ws_i + (size_t)N;              // N
    int* row_ptr = ws_i + (size_t)2 * N;          // N+1 (alloc N+4)
    int* cursor  = ws_i + (size_t)3 * N + 4;      // NBUCK (pad 1024)
    int* bsum    = ws_i + (size_t)3 * N + 1028;   // 512
    int* bsum_ex = ws_i + (size_t)3 * N + 1540;   // 512 -> end 3N+2052, round 3N+2056
    int* bin_sw  = ws_i + (size_t)3 * N + 2056;   // E
    float* bin_w = (float*)(ws_i + (size_t)3 * N + 2056 + (size_t)E); // E

    float* fbase = (float*)(ws_i + (size_t)3 * N + 2056 + 2 * (size_t)E);
    float* no_b  = fbase;                          // N
    float* ni_b  = fbase + (size_t)N;              // N
    float* xs    = fbase + (size_t)2 * N;          // 8N
    float* h1s   = fbase + (size_t)10 * N;         // 32N
    float* h2s   = fbase + (size_t)42 * N;         // 32N
    float2* h4pre = (float2*)(fbase + (size_t)74 * N); // 2N
    float2* agg2  = (float2*)(fbase + (size_t)76 * N); // 2N

    hipMemsetAsync(ws_i, 0, (size_t)2 * N * sizeof(int), stream);

    const int B = 256;
    k_hist<<<(E + B - 1) / B, B, 0, stream>>>(src, dst, cnt_out, cnt_in, E);
    k_scan_blocks<<<NB_SCAN, 256, 0, stream>>>(cnt_in, row_ptr, bsum, N);
    k_scan_top<<<1, 512, 0, stream>>>(bsum, bsum_ex, NB_SCAN);
    k_scan_add_prep<<<(N + 1 + B - 1) / B, B, 0, stream>>>(row_ptr, bsum_ex, cursor,
                                                           cnt_out, cnt_in, x, no_b, ni_b, xs, N, E);
    k_binpass<<<NTILES, 256, 0, stream>>>(src, dst, e, cursor, bin_sw, bin_w, E);

    k_layer1<<<NBUCK, 256, 0, stream>>>(row_ptr, bin_sw, bin_w, xs, ni_b, no_b, W1, b1, h1s, N);
    k_layer32<<<NBUCK, 512, 0, stream>>>(row_ptr, bin_sw, h1s, ni_b, no_b, W2, b2, h2s, N);
    k_layer34<<<NBUCK, 512, 0, stream>>>(row_ptr, bin_sw, h2s, ni_b, no_b, W3, b3, W4, h4pre, N);
    k_agg4<<<NBUCK, 256, 0, stream>>>(row_ptr, bin_sw, h4pre, ni_b, agg2, N);
    k_pool<<<G, 64, 0, stream>>>(agg2, gid, b4, out, N);
}

// Round 5
// 689.496 us; speedup vs baseline: 2.3855x; 2.3855x over previous
//
#include <hip/hip_runtime.h>

#define NN 100000
#define NE 2500000
#define NB_SCAN ((NN + 255) / 256)          // 391 scan blocks
#define BK_SHIFT 7
#define BK_NODES 128
#define NBUCK ((NN + BK_NODES - 1) / BK_NODES)   // 782
#define NBUCK_PAD 1024
#define TILE 4096
#define NTILES ((NE + TILE - 1) / TILE)     // 611
#define SRC_MASK 0x1FFFF                    // 17 bits, NN < 131072

// ---------------- degree histogram ----------------

__global__ void k_hist(const int* __restrict__ src, const int* __restrict__ dst,
                       int* __restrict__ cnt_out, int* __restrict__ cnt_in, int E) {
    int i = blockIdx.x * blockDim.x + threadIdx.x;
    if (i < E) {
        atomicAdd(&cnt_out[src[i]], 1);
        atomicAdd(&cnt_in[dst[i]], 1);
    }
}

// ---------------- row_ptr scan ----------------

__global__ void k_scan_blocks(const int* __restrict__ cnt, int* __restrict__ row_ptr,
                              int* __restrict__ bsum, int N) {
    __shared__ int sh[256];
    int i = blockIdx.x * 256 + threadIdx.x;
    int v = (i < N) ? cnt[i] : 0;
    sh[threadIdx.x] = v;
    __syncthreads();
#pragma unroll
    for (int off = 1; off < 256; off <<= 1) {
        int t = (threadIdx.x >= off) ? sh[threadIdx.x - off] : 0;
        __syncthreads();
        sh[threadIdx.x] += t;
        __syncthreads();
    }
    if (i < N) row_ptr[i] = sh[threadIdx.x] - v;  // exclusive, pre-offset
    if (threadIdx.x == 255) bsum[blockIdx.x] = sh[255];
}

__global__ void k_scan_top(const int* __restrict__ bsum, int* __restrict__ bsum_ex, int NB) {
    __shared__ int sh[512];
    int tid = threadIdx.x;
    int v = (tid < NB) ? bsum[tid] : 0;
    sh[tid] = v;
    __syncthreads();
#pragma unroll
    for (int off = 1; off < 512; off <<= 1) {
        int t = (tid >= off) ? sh[tid - off] : 0;
        __syncthreads();
        sh[tid] += t;
        __syncthreads();
    }
    if (tid < NB) bsum_ex[tid] = sh[tid] - v;
}

// add block offsets; init per-bucket cursor; row_ptr[N]=E; fused prep:
// norms from degrees + xs[n*8+f] = x[n*7+f]*norm_out (8-padded)
__global__ void k_scan_add_prep(int* __restrict__ row_ptr, const int* __restrict__ bsum_ex,
                                int* __restrict__ cursor, const int* __restrict__ cnt_out,
                                const int* __restrict__ cnt_in, const float* __restrict__ x,
                                float* __restrict__ no, float* __restrict__ ni,
                                float* __restrict__ xs, int N, int E) {
    int i = blockIdx.x * blockDim.x + threadIdx.x;
    if (i < N) {
        int r = row_ptr[i] + bsum_ex[i >> 8];
        row_ptr[i] = r;
        if ((i & (BK_NODES - 1)) == 0) cursor[i >> BK_SHIFT] = r;
        float nov = rsqrtf(fmaxf((float)cnt_out[i], 1.0f));
        float niv = rsqrtf(fmaxf((float)cnt_in[i], 1.0f));
        no[i] = nov;
        ni[i] = niv;
#pragma unroll
        for (int f = 0; f < 7; ++f) xs[i * 8 + f] = x[i * 7 + f] * nov;
        xs[i * 8 + 7] = 0.f;
    } else if (i == N) {
        row_ptr[N] = E;
    }
}

// ---------------- pass 1: bucket binning (dense coalesced writes) ----------------
// stage2[pos] = (src | dst_local<<17, weight_bits), grouped by 128-node bucket
__global__ __launch_bounds__(256) void k_binpass(
    const int* __restrict__ src, const int* __restrict__ dst, const float* __restrict__ ew,
    int* __restrict__ cursor, int2* __restrict__ stage2, int E) {
    __shared__ int cnt[NBUCK_PAD];
    __shared__ int offs[NBUCK_PAD];
    __shared__ int gpos[NBUCK_PAD];
    __shared__ int sc[256];
    __shared__ int2 st[TILE];
    __shared__ unsigned short stb[TILE];

    int base = blockIdx.x * TILE;
    int tn = E - base; if (tn > TILE) tn = TILE;

    for (int i = threadIdx.x; i < NBUCK_PAD; i += 256) cnt[i] = 0;
    __syncthreads();

    int myw0[16]; float myw1[16]; int myb[16]; int myr[16];
#pragma unroll
    for (int k = 0; k < 16; ++k) {
        int idx = base + threadIdx.x + k * 256;
        myb[k] = -1;
        if (idx < E) {
            int s = src[idx], d = dst[idx];
            myw1[k] = ew[idx];
            int b = d >> BK_SHIFT;
            myw0[k] = s | ((d & (BK_NODES - 1)) << 17);
            myb[k] = b;
            myr[k] = atomicAdd(&cnt[b], 1);
        }
    }
    __syncthreads();

    // block scan of cnt[0..NBUCK): 4 buckets per thread
    int t = threadIdx.x;
    int c0 = cnt[t * 4], c1 = cnt[t * 4 + 1], c2 = cnt[t * 4 + 2], c3 = cnt[t * 4 + 3];
    int tot = c0 + c1 + c2 + c3;
    sc[t] = tot;
    __syncthreads();
#pragma unroll
    for (int off = 1; off < 256; off <<= 1) {
        int v = (t >= off) ? sc[t - off] : 0;
        __syncthreads();
        sc[t] += v;
        __syncthreads();
    }
    int run = sc[t] - tot;
    {
        int b = t * 4;
        offs[b] = run;
        if (c0 > 0) gpos[b] = atomicAdd(&cursor[b], c0);
        run += c0;
        offs[b + 1] = run;
        if (c1 > 0) gpos[b + 1] = atomicAdd(&cursor[b + 1], c1);
        run += c1;
        offs[b + 2] = run;
        if (c2 > 0) gpos[b + 2] = atomicAdd(&cursor[b + 2], c2);
        run += c2;
        offs[b + 3] = run;
        if (c3 > 0) gpos[b + 3] = atomicAdd(&cursor[b + 3], c3);
    }
    __syncthreads();

    // stage into LDS grouped by bucket
#pragma unroll
    for (int k = 0; k < 16; ++k) {
        if (myb[k] >= 0) {
            int p = offs[myb[k]] + myr[k];
            st[p] = make_int2(myw0[k], __float_as_int(myw1[k]));
            stb[p] = (unsigned short)myb[k];
        }
    }
    __syncthreads();

    // flush contiguous per-bucket runs to per-bucket global regions
    for (int i = threadIdx.x; i < tn; i += 256) {
        int b = stb[i];
        int dest = gpos[b] + (i - offs[b]);
        stage2[dest] = st[i];
    }
}

// ---------------- pass 2: exact per-node CSR placement (bucket-local writes) ----------------
__global__ __launch_bounds__(256) void k_scatter2(
    const int* __restrict__ rp, const int2* __restrict__ stage2,
    int* __restrict__ csr_src, float* __restrict__ csr_w, int N) {
    __shared__ int cur[BK_NODES];
    int b = blockIdx.x;
    int base_n = b << BK_SHIFT;
    int beg = rp[base_n];
    int endn = base_n + BK_NODES; if (endn > N) endn = N;
    int end = rp[endn];
    if (threadIdx.x < BK_NODES) {
        int n = base_n + threadIdx.x;
        cur[threadIdx.x] = (n < N) ? rp[n] : 0;
    }
    __syncthreads();
    for (int j = beg + threadIdx.x; j < end; j += 256) {
        int2 t = stage2[j];
        int dl = t.x >> 17;
        int pos = atomicAdd(&cur[dl], 1);
        csr_src[pos] = t.x & SRC_MASK;
        csr_w[pos] = __int_as_float(t.y);
    }
}

// ---------------- fused layers (per-node shfl-walk gather, no atomics) ----------------

// layer 1: 8 lanes/node gather-aggregate (weighted), then 7->32 matmul epilogue.
__global__ __launch_bounds__(256) void k_layer1(
    const int* __restrict__ rp, const int* __restrict__ csr_src, const float* __restrict__ csr_w,
    const float* __restrict__ xs, const float* __restrict__ ni, const float* __restrict__ no,
    const float* __restrict__ W1, const float* __restrict__ b1, float* __restrict__ h1s, int N) {
    __shared__ float sW[7 * 32];
    __shared__ float sb[32];
    __shared__ float sh7[32][8];
    for (int i = threadIdx.x; i < 7 * 32; i += 256) sW[i] = W1[i];
    if (threadIdx.x < 32) sb[threadIdx.x] = b1[threadIdx.x];

    int g = threadIdx.x >> 3, lane = threadIdx.x & 7;
    int node = blockIdx.x * 32 + g;
    float acc = 0.f;
    if (node < N) {
        int beg = rp[node], end = rp[node + 1];
        for (int j0 = beg; j0 < end; j0 += 8) {
            int ms = 0; float mw = 0.f;
            if (j0 + lane < end) {
                ms = csr_src[j0 + lane];
                mw = csr_w[j0 + lane];
            }
            int m = end - j0; if (m > 8) m = 8;
            for (int k = 0; k < m; ++k) {
                int s = __shfl(ms, k, 8);
                float w = __shfl(mw, k, 8);
                acc += xs[s * 8 + lane] * w;
            }
        }
        acc *= ni[node];
    }
    sh7[g][lane] = acc;
    __syncthreads();

    int g2 = threadIdx.x >> 5, l32 = threadIdx.x & 31;
#pragma unroll
    for (int t = 0; t < 4; ++t) {
        int nl = t * 8 + g2;
        int node2 = blockIdx.x * 32 + nl;
        if (node2 < N) {
            float o = sb[l32];
#pragma unroll
            for (int k = 0; k < 7; ++k) o += sh7[nl][k] * sW[k * 32 + l32];
            h1s[node2 * 32 + l32] = fmaxf(o, 0.f) * no[node2];
        }
    }
}

// 32-wide layer: 32 lanes/node, shfl-batched CSR walk, coalesced 128B gather/edge,
// fused 32x32 matmul. h_out = relu((agg*ni) @ W + b) * no
__global__ __launch_bounds__(256) void k_layer32(
    const int* __restrict__ rp, const int* __restrict__ csr_src, const float* __restrict__ h_in,
    const float* __restrict__ ni, const float* __restrict__ no, const float* __restrict__ W,
    const float* __restrict__ b, float* __restrict__ h_out, int N) {
    __shared__ float sW[32 * 32];
    __shared__ float sb[32];
    __shared__ float shv[8][32];
    for (int i = threadIdx.x; i < 1024; i += 256) sW[i] = W[i];
    if (threadIdx.x < 32) sb[threadIdx.x] = b[threadIdx.x];

    int g = threadIdx.x >> 5, lane = threadIdx.x & 31;
    int node = blockIdx.x * 8 + g;
    float acc = 0.f;
    if (node < N) {
        int beg = rp[node], end = rp[node + 1];
        for (int j0 = beg; j0 < end; j0 += 32) {
            int ms = (j0 + lane < end) ? csr_src[j0 + lane] : 0;
            int m = end - j0; if (m > 32) m = 32;
            for (int k = 0; k < m; ++k) {
                int s = __shfl(ms, k, 32);
                acc += h_in[s * 32 + lane];
            }
        }
        acc *= ni[node];
    }
    shv[g][lane] = acc;
    __syncthreads();
    if (node < N) {
        float o = sb[lane];
#pragma unroll
        for (int k = 0; k < 32; ++k) o += shv[g][k] * sW[k * 32 + lane];
        h_out[node * 32 + lane] = fmaxf(o, 0.f) * no[node];
    }
}

// layer 3 + W4 pre-multiply: h4pre = (relu((agg*ni)@W3+b3)*no) @ W4   [per node, 2-dim]
__global__ __launch_bounds__(256) void k_layer34(
    const int* __restrict__ rp, const int* __restrict__ csr_src, const float* __restrict__ h_in,
    const float* __restrict__ ni, const float* __restrict__ no, const float* __restrict__ W3,
    const float* __restrict__ b3, const float* __restrict__ W4, float2* __restrict__ h4pre, int N) {
    __shared__ float sW[32 * 32];
    __shared__ float sb[32];
    __shared__ float sW4[64];
    __shared__ float shv[8][32];
    for (int i = threadIdx.x; i < 1024; i += 256) sW[i] = W3[i];
    if (threadIdx.x < 32) sb[threadIdx.x] = b3[threadIdx.x];
    if (threadIdx.x < 64) sW4[threadIdx.x] = W4[threadIdx.x];

    int g = threadIdx.x >> 5, lane = threadIdx.x & 31;
    int node = blockIdx.x * 8 + g;
    float acc = 0.f;
    if (node < N) {
        int beg = rp[node], end = rp[node + 1];
        for (int j0 = beg; j0 < end; j0 += 32) {
            int ms = (j0 + lane < end) ? csr_src[j0 + lane] : 0;
            int m = end - j0; if (m > 32) m = 32;
            for (int k = 0; k < m; ++k) {
                int s = __shfl(ms, k, 32);
                acc += h_in[s * 32 + lane];
            }
        }
        acc *= ni[node];
    }
    shv[g][lane] = acc;
    __syncthreads();
    if (node < N) {
        float o = sb[lane];
#pragma unroll
        for (int k = 0; k < 32; ++k) o += shv[g][k] * sW[k * 32 + lane];
        float t = fmaxf(o, 0.f) * no[node];
        float px = t * sW4[lane * 2 + 0];
        float py = t * sW4[lane * 2 + 1];
#pragma unroll
        for (int off = 16; off; off >>= 1) {
            px += __shfl_xor(px, off, 32);
            py += __shfl_xor(py, off, 32);
        }
        if (lane == 0) h4pre[node] = make_float2(px, py);
    }
}

// layer-4 aggregation in 2-dim, one thread/node; stores agg*ni
__global__ void k_agg4(const int* __restrict__ rp, const int* __restrict__ csr_src,
                       const float2* __restrict__ h4pre, const float* __restrict__ ni,
                       float2* __restrict__ agg2, int N) {
    int n = blockIdx.x * blockDim.x + threadIdx.x;
    if (n >= N) return;
    float ax = 0.f, ay = 0.f;
    int beg = rp[n], end = rp[n + 1];
    for (int j = beg; j < end; ++j) {
        float2 v = h4pre[csr_src[j]];
        ax += v.x;
        ay += v.y;
    }
    float w = ni[n];
    agg2[n] = make_float2(ax * w, ay * w);
}

// mean pooling: gid sorted -> one wave/graph, binary-search range
__global__ void k_pool(const float2* __restrict__ agg2, const int* __restrict__ gid,
                       const float* __restrict__ b4, float* __restrict__ out, int N) {
    int g = blockIdx.x;
    int lo = 0, hi = N;
    while (lo < hi) { int m = (lo + hi) >> 1; if (gid[m] < g) lo = m + 1; else hi = m; }
    int start = lo;
    int lo2 = start, hi2 = N;
    while (lo2 < hi2) { int m = (lo2 + hi2) >> 1; if (gid[m] < g + 1) lo2 = m + 1; else hi2 = m; }
    int end = lo2;
    float sx = 0.f, sy = 0.f;
    for (int n = start + threadIdx.x; n < end; n += 64) {
        float2 v = agg2[n];
        sx += v.x;
        sy += v.y;
    }
#pragma unroll
    for (int off = 32; off; off >>= 1) {
        sx += __shfl_down(sx, off, 64);
        sy += __shfl_down(sy, off, 64);
    }
    if (threadIdx.x == 0) {
        int cnt = end - start;
        float inv = 1.0f / fmaxf((float)cnt, 1.0f);
        float scale = (float)cnt * inv;  // 0 if empty, else 1
        out[g * 2 + 0] = sx * inv + b4[0] * scale;
        out[g * 2 + 1] = sy * inv + b4[1] * scale;
    }
}

// ---------------- launch ----------------

extern "C" void kernel_launch(void* const* d_in, const int* in_sizes, int n_in,
                              void* d_out, int out_size, void* d_ws, size_t ws_size,
                              hipStream_t stream) {
    const float* x   = (const float*)d_in[0];
    const float* e   = (const float*)d_in[1];
    const float* W1  = (const float*)d_in[2];
    const float* b1  = (const float*)d_in[3];
    const float* W2  = (const float*)d_in[4];
    const float* b2  = (const float*)d_in[5];
    const float* W3  = (const float*)d_in[6];
    const float* b3  = (const float*)d_in[7];
    const float* W4  = (const float*)d_in[8];
    const float* b4  = (const float*)d_in[9];
    const int*   src = (const int*)d_in[10];
    const int*   dst = (const int*)d_in[11];
    const int*   gid = (const int*)d_in[12];
    float* out = (float*)d_out;

    const int N = NN, E = NE;
    const int G = out_size / 2;

    int* ws_i = (int*)d_ws;
    int* cnt_out = ws_i;                          // N
    int* cnt_in  = ws_i + (size_t)N;              // N
    int* row_ptr = ws_i + (size_t)2 * N;          // N+1 (alloc N+4)
    int* cursor  = ws_i + (size_t)3 * N + 4;      // NBUCK (pad 1024)
    int* bsum    = ws_i + (size_t)3 * N + 1028;   // 512
    int* bsum_ex = ws_i + (size_t)3 * N + 1540;   // 512 -> end 3N+2052, round 3N+2056
    int* csr_src = ws_i + (size_t)3 * N + 2056;   // E
    float* csr_w = (float*)(ws_i + (size_t)3 * N + 2056 + (size_t)E); // E

    float* fbase = (float*)(ws_i + (size_t)3 * N + 2056 + 2 * (size_t)E);
    float* no_b  = fbase;                          // N
    float* ni_b  = fbase + (size_t)N;              // N
    float* xs    = fbase + (size_t)2 * N;          // 8N
    float* h1s   = fbase + (size_t)10 * N;         // 32N
    float* h2s   = fbase + (size_t)42 * N;         // 32N
    float2* h4pre = (float2*)(fbase + (size_t)74 * N); // 2N
    float2* agg2  = (float2*)(fbase + (size_t)76 * N); // 2N
    // stage2 aliased over h1s/h2s (dead by the time layer1 writes h1s):
    int2* stage2 = (int2*)(fbase + (size_t)10 * N);    // E int2 = 5M ints < 64N

    hipMemsetAsync(ws_i, 0, (size_t)2 * N * sizeof(int), stream);

    const int B = 256;
    k_hist<<<(E + B - 1) / B, B, 0, stream>>>(src, dst, cnt_out, cnt_in, E);
    k_scan_blocks<<<NB_SCAN, 256, 0, stream>>>(cnt_in, row_ptr, bsum, N);
    k_scan_top<<<1, 512, 0, stream>>>(bsum, bsum_ex, NB_SCAN);
    k_scan_add_prep<<<(N + 1 + B - 1) / B, B, 0, stream>>>(row_ptr, bsum_ex, cursor,
                                                           cnt_out, cnt_in, x, no_b, ni_b, xs, N, E);
    k_binpass<<<NTILES, 256, 0, stream>>>(src, dst, e, cursor, stage2, E);
    k_scatter2<<<NBUCK, 256, 0, stream>>>(row_ptr, stage2, csr_src, csr_w, N);

    k_layer1<<<(N + 31) / 32, 256, 0, stream>>>(row_ptr, csr_src, csr_w, xs, ni_b, no_b, W1, b1, h1s, N);
    k_layer32<<<(N + 7) / 8, 256, 0, stream>>>(row_ptr, csr_src, h1s, ni_b, no_b, W2, b2, h2s, N);
    k_layer34<<<(N + 7) / 8, 256, 0, stream>>>(row_ptr, csr_src, h2s, ni_b, no_b, W3, b3, W4, h4pre, N);
    k_agg4<<<(N + B - 1) / B, B, 0, stream>>>(row_ptr, csr_src, h4pre, ni_b, agg2, N);
    k_pool<<<G, 64, 0, stream>>>(agg2, gid, b4, out, N);
}

// Round 6
// 594.039 us; speedup vs baseline: 2.7688x; 1.1607x over previous
//
#include <hip/hip_runtime.h>

#define NN 100000
#define NE 2500000
#define BK_SHIFT 7
#define BK_NODES 128
#define NBUCK ((NN + BK_NODES - 1) / BK_NODES)   // 782
#define NBUCK_PAD 1024
#define TILE 4096
#define NTILES ((NE + TILE - 1) / TILE)     // 611
#define SRC_MASK 0x1FFFF                    // 17 bits, NN < 131072

// ---------------- CSR build, no global random atomics ----------------

// per-tile bucket histograms (dst and src), dense coalesced output
__global__ __launch_bounds__(256) void k_tilecnt(const int* __restrict__ src,
                                                 const int* __restrict__ dst,
                                                 int* __restrict__ tc_d, int* __restrict__ tc_s,
                                                 int E) {
    __shared__ int cd[NBUCK];
    __shared__ int cs[NBUCK];
    int base = blockIdx.x * TILE;
    for (int i = threadIdx.x; i < NBUCK; i += 256) { cd[i] = 0; cs[i] = 0; }
    __syncthreads();
#pragma unroll
    for (int k = 0; k < 16; ++k) {
        int idx = base + threadIdx.x + k * 256;
        if (idx < E) {
            atomicAdd(&cd[dst[idx] >> BK_SHIFT], 1);
            atomicAdd(&cs[src[idx] >> BK_SHIFT], 1);
        }
    }
    __syncthreads();
    size_t rb = (size_t)blockIdx.x * NBUCK;
    for (int i = threadIdx.x; i < NBUCK; i += 256) {
        tc_d[rb + i] = cd[i];
        tc_s[rb + i] = cs[i];
    }
}

// column totals: one block per (which, bucket)
__global__ __launch_bounds__(256) void k_coltot(const int* __restrict__ tc_d,
                                                const int* __restrict__ tc_s,
                                                int* __restrict__ tot_d, int* __restrict__ tot_s) {
    __shared__ int red[256];
    int b = blockIdx.x;
    int which = (b >= NBUCK);
    if (which) b -= NBUCK;
    const int* tc = which ? tc_s : tc_d;
    int s = 0;
    for (int t = threadIdx.x; t < NTILES; t += 256) s += tc[(size_t)t * NBUCK + b];
    red[threadIdx.x] = s;
    __syncthreads();
    for (int o = 128; o; o >>= 1) {
        if (threadIdx.x < o) red[threadIdx.x] += red[threadIdx.x + o];
        __syncthreads();
    }
    if (threadIdx.x == 0) (which ? tot_s : tot_d)[b] = red[0];
}

// single-block scan of both bucket-total arrays -> bases + cursor init; row_ptr[N]=E
__global__ __launch_bounds__(1024) void k_bucket_scan(const int* __restrict__ tot_d,
                                                      const int* __restrict__ tot_s,
                                                      int* __restrict__ base_d, int* __restrict__ base_s,
                                                      int* __restrict__ cursor_d, int* __restrict__ cursor_s,
                                                      int* __restrict__ row_ptr, int E) {
    __shared__ int sh[1024];
    int tid = threadIdx.x;
    // dst
    int v = (tid < NBUCK) ? tot_d[tid] : 0;
    sh[tid] = v;
    __syncthreads();
#pragma unroll
    for (int off = 1; off < 1024; off <<= 1) {
        int t = (tid >= off) ? sh[tid - off] : 0;
        __syncthreads();
        sh[tid] += t;
        __syncthreads();
    }
    if (tid < NBUCK) { int ex = sh[tid] - v; base_d[tid] = ex; cursor_d[tid] = ex; }
    if (tid == 0) { base_d[NBUCK] = E; row_ptr[NN] = E; }
    __syncthreads();
    // src
    v = (tid < NBUCK) ? tot_s[tid] : 0;
    sh[tid] = v;
    __syncthreads();
#pragma unroll
    for (int off = 1; off < 1024; off <<= 1) {
        int t = (tid >= off) ? sh[tid - off] : 0;
        __syncthreads();
        sh[tid] += t;
        __syncthreads();
    }
    if (tid < NBUCK) { int ex = sh[tid] - v; base_s[tid] = ex; cursor_s[tid] = ex; }
    if (tid == 0) base_s[NBUCK] = E;
}

// bin edges by dst-bucket: stage2[pos] = (src | dst_local<<17, weight_bits)
__global__ __launch_bounds__(256) void k_binpass(
    const int* __restrict__ src, const int* __restrict__ dst, const float* __restrict__ ew,
    int* __restrict__ cursor, int2* __restrict__ stage2, int E) {
    __shared__ int cnt[NBUCK_PAD];
    __shared__ int offs[NBUCK_PAD];
    __shared__ int gpos[NBUCK_PAD];
    __shared__ int sc[256];
    __shared__ int2 st[TILE];
    __shared__ unsigned short stb[TILE];

    int base = blockIdx.x * TILE;
    int tn = E - base; if (tn > TILE) tn = TILE;

    for (int i = threadIdx.x; i < NBUCK_PAD; i += 256) cnt[i] = 0;
    __syncthreads();

    int myw0[16]; float myw1[16]; int myb[16]; int myr[16];
#pragma unroll
    for (int k = 0; k < 16; ++k) {
        int idx = base + threadIdx.x + k * 256;
        myb[k] = -1;
        if (idx < E) {
            int s = src[idx], d = dst[idx];
            myw1[k] = ew[idx];
            int b = d >> BK_SHIFT;
            myw0[k] = s | ((d & (BK_NODES - 1)) << 17);
            myb[k] = b;
            myr[k] = atomicAdd(&cnt[b], 1);
        }
    }
    __syncthreads();

    int t = threadIdx.x;
    int c0 = cnt[t * 4], c1 = cnt[t * 4 + 1], c2 = cnt[t * 4 + 2], c3 = cnt[t * 4 + 3];
    int tot = c0 + c1 + c2 + c3;
    sc[t] = tot;
    __syncthreads();
#pragma unroll
    for (int off = 1; off < 256; off <<= 1) {
        int v = (t >= off) ? sc[t - off] : 0;
        __syncthreads();
        sc[t] += v;
        __syncthreads();
    }
    int run = sc[t] - tot;
    {
        int b = t * 4;
        offs[b] = run;
        if (c0 > 0) gpos[b] = atomicAdd(&cursor[b], c0);
        run += c0;
        offs[b + 1] = run;
        if (c1 > 0) gpos[b + 1] = atomicAdd(&cursor[b + 1], c1);
        run += c1;
        offs[b + 2] = run;
        if (c2 > 0) gpos[b + 2] = atomicAdd(&cursor[b + 2], c2);
        run += c2;
        offs[b + 3] = run;
        if (c3 > 0) gpos[b + 3] = atomicAdd(&cursor[b + 3], c3);
    }
    __syncthreads();

#pragma unroll
    for (int k = 0; k < 16; ++k) {
        if (myb[k] >= 0) {
            int p = offs[myb[k]] + myr[k];
            st[p] = make_int2(myw0[k], __float_as_int(myw1[k]));
            stb[p] = (unsigned short)myb[k];
        }
    }
    __syncthreads();

    for (int i = threadIdx.x; i < tn; i += 256) {
        int b = stb[i];
        int dest = gpos[b] + (i - offs[b]);
        stage2[dest] = st[i];
    }
}

// bin src ids by src-bucket: stage_s[pos] = src_local (0..127)
__global__ __launch_bounds__(256) void k_binpass_src(
    const int* __restrict__ src, int* __restrict__ cursor, int* __restrict__ stage_s, int E) {
    __shared__ int cnt[NBUCK_PAD];
    __shared__ int offs[NBUCK_PAD];
    __shared__ int gpos[NBUCK_PAD];
    __shared__ int sc[256];
    __shared__ int st[TILE];
    __shared__ unsigned short stb[TILE];

    int base = blockIdx.x * TILE;
    int tn = E - base; if (tn > TILE) tn = TILE;

    for (int i = threadIdx.x; i < NBUCK_PAD; i += 256) cnt[i] = 0;
    __syncthreads();

    int myv[16]; int myb[16]; int myr[16];
#pragma unroll
    for (int k = 0; k < 16; ++k) {
        int idx = base + threadIdx.x + k * 256;
        myb[k] = -1;
        if (idx < E) {
            int s = src[idx];
            int b = s >> BK_SHIFT;
            myv[k] = s & (BK_NODES - 1);
            myb[k] = b;
            myr[k] = atomicAdd(&cnt[b], 1);
        }
    }
    __syncthreads();

    int t = threadIdx.x;
    int c0 = cnt[t * 4], c1 = cnt[t * 4 + 1], c2 = cnt[t * 4 + 2], c3 = cnt[t * 4 + 3];
    int tot = c0 + c1 + c2 + c3;
    sc[t] = tot;
    __syncthreads();
#pragma unroll
    for (int off = 1; off < 256; off <<= 1) {
        int v = (t >= off) ? sc[t - off] : 0;
        __syncthreads();
        sc[t] += v;
        __syncthreads();
    }
    int run = sc[t] - tot;
    {
        int b = t * 4;
        offs[b] = run;
        if (c0 > 0) gpos[b] = atomicAdd(&cursor[b], c0);
        run += c0;
        offs[b + 1] = run;
        if (c1 > 0) gpos[b + 1] = atomicAdd(&cursor[b + 1], c1);
        run += c1;
        offs[b + 2] = run;
        if (c2 > 0) gpos[b + 2] = atomicAdd(&cursor[b + 2], c2);
        run += c2;
        offs[b + 3] = run;
        if (c3 > 0) gpos[b + 3] = atomicAdd(&cursor[b + 3], c3);
    }
    __syncthreads();

#pragma unroll
    for (int k = 0; k < 16; ++k) {
        if (myb[k] >= 0) {
            int p = offs[myb[k]] + myr[k];
            st[p] = myv[k];
            stb[p] = (unsigned short)myb[k];
        }
    }
    __syncthreads();

    for (int i = threadIdx.x; i < tn; i += 256) {
        int b = stb[i];
        int dest = gpos[b] + (i - offs[b]);
        stage_s[dest] = st[i];
    }
}

// per-bucket: count src occurrences -> deg_out -> no[n], xs[n*8+f]=x*no (8-padded)
__global__ __launch_bounds__(256) void k_prep_src(
    const int* __restrict__ base_s, const int* __restrict__ stage_s, const float* __restrict__ x,
    float* __restrict__ no, float* __restrict__ xs, int N) {
    __shared__ int cnt[BK_NODES];
    int b = blockIdx.x;
    int beg = base_s[b], end = base_s[b + 1];
    if (threadIdx.x < BK_NODES) cnt[threadIdx.x] = 0;
    __syncthreads();
    for (int j = beg + threadIdx.x; j < end; j += 256) atomicAdd(&cnt[stage_s[j]], 1);
    __syncthreads();
    if (threadIdx.x < BK_NODES) {
        int n = (b << BK_SHIFT) + threadIdx.x;
        if (n < N) {
            float nov = rsqrtf(fmaxf((float)cnt[threadIdx.x], 1.0f));
            no[n] = nov;
#pragma unroll
            for (int f = 0; f < 7; ++f) xs[n * 8 + f] = x[n * 7 + f] * nov;
            xs[n * 8 + 7] = 0.f;
        }
    }
}

// per-bucket: count dst -> deg_in -> ni, local scan -> row_ptr, then exact CSR placement
__global__ __launch_bounds__(256) void k_scatter2(
    const int* __restrict__ base_d, const int2* __restrict__ stage2,
    int* __restrict__ row_ptr, float* __restrict__ ni,
    int* __restrict__ csr_src, float* __restrict__ csr_w, int N) {
    __shared__ int cnt[BK_NODES];
    __shared__ int scn[BK_NODES];
    __shared__ int cur[BK_NODES];
    int b = blockIdx.x;
    int beg = base_d[b], end = base_d[b + 1];
    if (threadIdx.x < BK_NODES) cnt[threadIdx.x] = 0;
    __syncthreads();
    for (int j = beg + threadIdx.x; j < end; j += 256) atomicAdd(&cnt[stage2[j].x >> 17], 1);
    __syncthreads();
    int v = (threadIdx.x < BK_NODES) ? cnt[threadIdx.x] : 0;
    if (threadIdx.x < BK_NODES) scn[threadIdx.x] = v;
    __syncthreads();
#pragma unroll
    for (int off = 1; off < BK_NODES; off <<= 1) {
        int t = (threadIdx.x < BK_NODES && threadIdx.x >= off) ? scn[threadIdx.x - off] : 0;
        __syncthreads();
        if (threadIdx.x < BK_NODES) scn[threadIdx.x] += t;
        __syncthreads();
    }
    if (threadIdx.x < BK_NODES) {
        int ex = scn[threadIdx.x] - v;
        cur[threadIdx.x] = beg + ex;
        int n = (b << BK_SHIFT) + threadIdx.x;
        if (n < N) {
            row_ptr[n] = beg + ex;
            ni[n] = rsqrtf(fmaxf((float)v, 1.0f));
        }
    }
    __syncthreads();
    for (int j = beg + threadIdx.x; j < end; j += 256) {
        int2 t = stage2[j];
        int dl = t.x >> 17;
        int pos = atomicAdd(&cur[dl], 1);
        csr_src[pos] = t.x & SRC_MASK;
        csr_w[pos] = __int_as_float(t.y);
    }
}

// ---------------- fused layers (per-node shfl-walk gather, no atomics) ----------------

__global__ __launch_bounds__(256) void k_layer1(
    const int* __restrict__ rp, const int* __restrict__ csr_src, const float* __restrict__ csr_w,
    const float* __restrict__ xs, const float* __restrict__ ni, const float* __restrict__ no,
    const float* __restrict__ W1, const float* __restrict__ b1, float* __restrict__ h1s, int N) {
    __shared__ float sW[7 * 32];
    __shared__ float sb[32];
    __shared__ float sh7[32][8];
    for (int i = threadIdx.x; i < 7 * 32; i += 256) sW[i] = W1[i];
    if (threadIdx.x < 32) sb[threadIdx.x] = b1[threadIdx.x];

    int g = threadIdx.x >> 3, lane = threadIdx.x & 7;
    int node = blockIdx.x * 32 + g;
    float acc = 0.f;
    if (node < N) {
        int beg = rp[node], end = rp[node + 1];
        for (int j0 = beg; j0 < end; j0 += 8) {
            int ms = 0; float mw = 0.f;
            if (j0 + lane < end) {
                ms = csr_src[j0 + lane];
                mw = csr_w[j0 + lane];
            }
            int m = end - j0; if (m > 8) m = 8;
            for (int k = 0; k < m; ++k) {
                int s = __shfl(ms, k, 8);
                float w = __shfl(mw, k, 8);
                acc += xs[s * 8 + lane] * w;
            }
        }
        acc *= ni[node];
    }
    sh7[g][lane] = acc;
    __syncthreads();

    int g2 = threadIdx.x >> 5, l32 = threadIdx.x & 31;
#pragma unroll
    for (int t = 0; t < 4; ++t) {
        int nl = t * 8 + g2;
        int node2 = blockIdx.x * 32 + nl;
        if (node2 < N) {
            float o = sb[l32];
#pragma unroll
            for (int k = 0; k < 7; ++k) o += sh7[nl][k] * sW[k * 32 + l32];
            h1s[node2 * 32 + l32] = fmaxf(o, 0.f) * no[node2];
        }
    }
}

__global__ __launch_bounds__(256) void k_layer32(
    const int* __restrict__ rp, const int* __restrict__ csr_src, const float* __restrict__ h_in,
    const float* __restrict__ ni, const float* __restrict__ no, const float* __restrict__ W,
    const float* __restrict__ b, float* __restrict__ h_out, int N) {
    __shared__ float sW[32 * 32];
    __shared__ float sb[32];
    __shared__ float shv[8][32];
    for (int i = threadIdx.x; i < 1024; i += 256) sW[i] = W[i];
    if (threadIdx.x < 32) sb[threadIdx.x] = b[threadIdx.x];

    int g = threadIdx.x >> 5, lane = threadIdx.x & 31;
    int node = blockIdx.x * 8 + g;
    float acc = 0.f;
    if (node < N) {
        int beg = rp[node], end = rp[node + 1];
        for (int j0 = beg; j0 < end; j0 += 32) {
            int ms = (j0 + lane < end) ? csr_src[j0 + lane] : 0;
            int m = end - j0; if (m > 32) m = 32;
            for (int k = 0; k < m; ++k) {
                int s = __shfl(ms, k, 32);
                acc += h_in[s * 32 + lane];
            }
        }
        acc *= ni[node];
    }
    shv[g][lane] = acc;
    __syncthreads();
    if (node < N) {
        float o = sb[lane];
#pragma unroll
        for (int k = 0; k < 32; ++k) o += shv[g][k] * sW[k * 32 + lane];
        h_out[node * 32 + lane] = fmaxf(o, 0.f) * no[node];
    }
}

__global__ __launch_bounds__(256) void k_layer34(
    const int* __restrict__ rp, const int* __restrict__ csr_src, const float* __restrict__ h_in,
    const float* __restrict__ ni, const float* __restrict__ no, const float* __restrict__ W3,
    const float* __restrict__ b3, const float* __restrict__ W4, float2* __restrict__ h4pre, int N) {
    __shared__ float sW[32 * 32];
    __shared__ float sb[32];
    __shared__ float sW4[64];
    __shared__ float shv[8][32];
    for (int i = threadIdx.x; i < 1024; i += 256) sW[i] = W3[i];
    if (threadIdx.x < 32) sb[threadIdx.x] = b3[threadIdx.x];
    if (threadIdx.x < 64) sW4[threadIdx.x] = W4[threadIdx.x];

    int g = threadIdx.x >> 5, lane = threadIdx.x & 31;
    int node = blockIdx.x * 8 + g;
    float acc = 0.f;
    if (node < N) {
        int beg = rp[node], end = rp[node + 1];
        for (int j0 = beg; j0 < end; j0 += 32) {
            int ms = (j0 + lane < end) ? csr_src[j0 + lane] : 0;
            int m = end - j0; if (m > 32) m = 32;
            for (int k = 0; k < m; ++k) {
                int s = __shfl(ms, k, 32);
                acc += h_in[s * 32 + lane];
            }
        }
        acc *= ni[node];
    }
    shv[g][lane] = acc;
    __syncthreads();
    if (node < N) {
        float o = sb[lane];
#pragma unroll
        for (int k = 0; k < 32; ++k) o += shv[g][k] * sW[k * 32 + lane];
        float t = fmaxf(o, 0.f) * no[node];
        float px = t * sW4[lane * 2 + 0];
        float py = t * sW4[lane * 2 + 1];
#pragma unroll
        for (int off = 16; off; off >>= 1) {
            px += __shfl_xor(px, off, 32);
            py += __shfl_xor(py, off, 32);
        }
        if (lane == 0) h4pre[node] = make_float2(px, py);
    }
}

__global__ void k_agg4(const int* __restrict__ rp, const int* __restrict__ csr_src,
                       const float2* __restrict__ h4pre, const float* __restrict__ ni,
                       float2* __restrict__ agg2, int N) {
    int n = blockIdx.x * blockDim.x + threadIdx.x;
    if (n >= N) return;
    float ax = 0.f, ay = 0.f;
    int beg = rp[n], end = rp[n + 1];
    for (int j = beg; j < end; ++j) {
        float2 v = h4pre[csr_src[j]];
        ax += v.x;
        ay += v.y;
    }
    float w = ni[n];
    agg2[n] = make_float2(ax * w, ay * w);
}

__global__ void k_pool(const float2* __restrict__ agg2, const int* __restrict__ gid,
                       const float* __restrict__ b4, float* __restrict__ out, int N) {
    int g = blockIdx.x;
    int lo = 0, hi = N;
    while (lo < hi) { int m = (lo + hi) >> 1; if (gid[m] < g) lo = m + 1; else hi = m; }
    int start = lo;
    int lo2 = start, hi2 = N;
    while (lo2 < hi2) { int m = (lo2 + hi2) >> 1; if (gid[m] < g + 1) lo2 = m + 1; else hi2 = m; }
    int end = lo2;
    float sx = 0.f, sy = 0.f;
    for (int n = start + threadIdx.x; n < end; n += 64) {
        float2 v = agg2[n];
        sx += v.x;
        sy += v.y;
    }
#pragma unroll
    for (int off = 32; off; off >>= 1) {
        sx += __shfl_down(sx, off, 64);
        sy += __shfl_down(sy, off, 64);
    }
    if (threadIdx.x == 0) {
        int cnt = end - start;
        float inv = 1.0f / fmaxf((float)cnt, 1.0f);
        float scale = (float)cnt * inv;  // 0 if empty, else 1
        out[g * 2 + 0] = sx * inv + b4[0] * scale;
        out[g * 2 + 1] = sy * inv + b4[1] * scale;
    }
}

// ---------------- launch ----------------

extern "C" void kernel_launch(void* const* d_in, const int* in_sizes, int n_in,
                              void* d_out, int out_size, void* d_ws, size_t ws_size,
                              hipStream_t stream) {
    const float* x   = (const float*)d_in[0];
    const float* e   = (const float*)d_in[1];
    const float* W1  = (const float*)d_in[2];
    const float* b1  = (const float*)d_in[3];
    const float* W2  = (const float*)d_in[4];
    const float* b2  = (const float*)d_in[5];
    const float* W3  = (const float*)d_in[6];
    const float* b3  = (const float*)d_in[7];
    const float* W4  = (const float*)d_in[8];
    const float* b4  = (const float*)d_in[9];
    const int*   src = (const int*)d_in[10];
    const int*   dst = (const int*)d_in[11];
    const int*   gid = (const int*)d_in[12];
    float* out = (float*)d_out;

    const int N = NN, E = NE;
    const int G = out_size / 2;

    const size_t TC = ((size_t)NTILES * NBUCK + 3) & ~(size_t)3;  // 477,804

    int* ws_i = (int*)d_ws;
    int* tc_d     = ws_i;                         // TC
    int* tc_s     = ws_i + TC;                    // TC
    int* tot_d    = ws_i + 2 * TC;                // 1024
    int* tot_s    = ws_i + 2 * TC + 1024;         // 1024
    int* base_d   = ws_i + 2 * TC + 2048;         // 1024 (need 783)
    int* base_s   = ws_i + 2 * TC + 3072;         // 1024
    int* cursor_d = ws_i + 2 * TC + 4096;         // 1024
    int* cursor_s = ws_i + 2 * TC + 5120;         // 1024
    int* row_ptr  = ws_i + 2 * TC + 6144;         // N+4
    int* csr_src  = ws_i + 2 * TC + 6144 + (size_t)N + 4;       // E
    float* csr_w  = (float*)(ws_i + 2 * TC + 6144 + (size_t)N + 4 + (size_t)E); // E
    int* stage_s  = (int*)csr_w;                  // alias: dead before csr_w written

    float* fbase = (float*)(ws_i + 2 * TC + 6144 + (size_t)N + 4 + 2 * (size_t)E);
    float* no_b  = fbase;                          // N
    float* ni_b  = fbase + (size_t)N;              // N
    float* xs    = fbase + (size_t)2 * N;          // 8N
    float* h1s   = fbase + (size_t)10 * N;         // 32N
    float* h2s   = fbase + (size_t)42 * N;         // 32N
    float2* h4pre = (float2*)(fbase + (size_t)74 * N); // 2N
    float2* agg2  = (float2*)(fbase + (size_t)76 * N); // 2N
    // stage2 aliased over h1s/h2s (2E ints = 5M <= 64N = 6.4M; dead before layer1 writes h1s)
    int2* stage2 = (int2*)(fbase + (size_t)10 * N);

    k_tilecnt<<<NTILES, 256, 0, stream>>>(src, dst, tc_d, tc_s, E);
    k_coltot<<<2 * NBUCK, 256, 0, stream>>>(tc_d, tc_s, tot_d, tot_s);
    k_bucket_scan<<<1, 1024, 0, stream>>>(tot_d, tot_s, base_d, base_s, cursor_d, cursor_s, row_ptr, E);
    k_binpass<<<NTILES, 256, 0, stream>>>(src, dst, e, cursor_d, stage2, E);
    k_binpass_src<<<NTILES, 256, 0, stream>>>(src, cursor_s, stage_s, E);
    k_prep_src<<<NBUCK, 256, 0, stream>>>(base_s, stage_s, x, no_b, xs, N);
    k_scatter2<<<NBUCK, 256, 0, stream>>>(base_d, stage2, row_ptr, ni_b, csr_src, csr_w, N);

    k_layer1<<<(N + 31) / 32, 256, 0, stream>>>(row_ptr, csr_src, csr_w, xs, ni_b, no_b, W1, b1, h1s, N);
    k_layer32<<<(N + 7) / 8, 256, 0, stream>>>(row_ptr, csr_src, h1s, ni_b, no_b, W2, b2, h2s, N);
    k_layer34<<<(N + 7) / 8, 256, 0, stream>>>(row_ptr, csr_src, h2s, ni_b, no_b, W3, b3, W4, h4pre, N);
    k_agg4<<<(N + 255) / 256, 256, 0, stream>>>(row_ptr, csr_src, h4pre, ni_b, agg2, N);
    k_pool<<<G, 64, 0, stream>>>(agg2, gid, b4, out, N);
}

// Round 7
// 523.937 us; speedup vs baseline: 3.1393x; 1.1338x over previous
//
#include <hip/hip_runtime.h>

#define NN 100000
#define NE 2500000
#define BK_SHIFT 7
#define BK_NODES 128
#define NBUCK ((NN + BK_NODES - 1) / BK_NODES)   // 782
#define NBUCK_PAD 1024
#define TILE 4096
#define NTILES ((NE + TILE - 1) / TILE)     // 611
#define SRC_MASK 0x1FFFF                    // 17 bits, NN < 131072

// ---------------- CSR build, no global random atomics ----------------

// per-tile bucket histograms (dst and src), dense coalesced output
__global__ __launch_bounds__(256) void k_tilecnt(const int* __restrict__ src,
                                                 const int* __restrict__ dst,
                                                 int* __restrict__ tc_d, int* __restrict__ tc_s,
                                                 int E) {
    __shared__ int cd[NBUCK];
    __shared__ int cs[NBUCK];
    int base = blockIdx.x * TILE;
    for (int i = threadIdx.x; i < NBUCK; i += 256) { cd[i] = 0; cs[i] = 0; }
    __syncthreads();
#pragma unroll
    for (int k = 0; k < 16; ++k) {
        int idx = base + threadIdx.x + k * 256;
        if (idx < E) {
            atomicAdd(&cd[dst[idx] >> BK_SHIFT], 1);
            atomicAdd(&cs[src[idx] >> BK_SHIFT], 1);
        }
    }
    __syncthreads();
    size_t rb = (size_t)blockIdx.x * NBUCK;
    for (int i = threadIdx.x; i < NBUCK; i += 256) {
        tc_d[rb + i] = cd[i];
        tc_s[rb + i] = cs[i];
    }
}

// column totals: one block per (which, bucket)
__global__ __launch_bounds__(256) void k_coltot(const int* __restrict__ tc_d,
                                                const int* __restrict__ tc_s,
                                                int* __restrict__ tot_d, int* __restrict__ tot_s) {
    __shared__ int red[256];
    int b = blockIdx.x;
    int which = (b >= NBUCK);
    if (which) b -= NBUCK;
    const int* tc = which ? tc_s : tc_d;
    int s = 0;
    for (int t = threadIdx.x; t < NTILES; t += 256) s += tc[(size_t)t * NBUCK + b];
    red[threadIdx.x] = s;
    __syncthreads();
    for (int o = 128; o; o >>= 1) {
        if (threadIdx.x < o) red[threadIdx.x] += red[threadIdx.x + o];
        __syncthreads();
    }
    if (threadIdx.x == 0) (which ? tot_s : tot_d)[b] = red[0];
}

// single-block scan of both bucket-total arrays -> bases + cursor init; row_ptr[N]=E
__global__ __launch_bounds__(1024) void k_bucket_scan(const int* __restrict__ tot_d,
                                                      const int* __restrict__ tot_s,
                                                      int* __restrict__ base_d, int* __restrict__ base_s,
                                                      int* __restrict__ cursor_d, int* __restrict__ cursor_s,
                                                      int* __restrict__ row_ptr, int E) {
    __shared__ int sh[1024];
    int tid = threadIdx.x;
    // dst
    int v = (tid < NBUCK) ? tot_d[tid] : 0;
    sh[tid] = v;
    __syncthreads();
#pragma unroll
    for (int off = 1; off < 1024; off <<= 1) {
        int t = (tid >= off) ? sh[tid - off] : 0;
        __syncthreads();
        sh[tid] += t;
        __syncthreads();
    }
    if (tid < NBUCK) { int ex = sh[tid] - v; base_d[tid] = ex; cursor_d[tid] = ex; }
    if (tid == 0) { base_d[NBUCK] = E; row_ptr[NN] = E; }
    __syncthreads();
    // src
    v = (tid < NBUCK) ? tot_s[tid] : 0;
    sh[tid] = v;
    __syncthreads();
#pragma unroll
    for (int off = 1; off < 1024; off <<= 1) {
        int t = (tid >= off) ? sh[tid - off] : 0;
        __syncthreads();
        sh[tid] += t;
        __syncthreads();
    }
    if (tid < NBUCK) { int ex = sh[tid] - v; base_s[tid] = ex; cursor_s[tid] = ex; }
    if (tid == 0) base_s[NBUCK] = E;
}

// bin edges by dst-bucket: stage2[pos] = (src | dst_local<<17, weight_bits)
__global__ __launch_bounds__(256) void k_binpass(
    const int* __restrict__ src, const int* __restrict__ dst, const float* __restrict__ ew,
    int* __restrict__ cursor, int2* __restrict__ stage2, int E) {
    __shared__ int cnt[NBUCK_PAD];
    __shared__ int offs[NBUCK_PAD];
    __shared__ int gpos[NBUCK_PAD];
    __shared__ int sc[256];
    __shared__ int2 st[TILE];
    __shared__ unsigned short stb[TILE];

    int base = blockIdx.x * TILE;
    int tn = E - base; if (tn > TILE) tn = TILE;

    for (int i = threadIdx.x; i < NBUCK_PAD; i += 256) cnt[i] = 0;
    __syncthreads();

    int myw0[16]; float myw1[16]; int myb[16]; int myr[16];
#pragma unroll
    for (int k = 0; k < 16; ++k) {
        int idx = base + threadIdx.x + k * 256;
        myb[k] = -1;
        if (idx < E) {
            int s = src[idx], d = dst[idx];
            myw1[k] = ew[idx];
            int b = d >> BK_SHIFT;
            myw0[k] = s | ((d & (BK_NODES - 1)) << 17);
            myb[k] = b;
            myr[k] = atomicAdd(&cnt[b], 1);
        }
    }
    __syncthreads();

    int t = threadIdx.x;
    int c0 = cnt[t * 4], c1 = cnt[t * 4 + 1], c2 = cnt[t * 4 + 2], c3 = cnt[t * 4 + 3];
    int tot = c0 + c1 + c2 + c3;
    sc[t] = tot;
    __syncthreads();
#pragma unroll
    for (int off = 1; off < 256; off <<= 1) {
        int v = (t >= off) ? sc[t - off] : 0;
        __syncthreads();
        sc[t] += v;
        __syncthreads();
    }
    int run = sc[t] - tot;
    {
        int b = t * 4;
        offs[b] = run;
        if (c0 > 0) gpos[b] = atomicAdd(&cursor[b], c0);
        run += c0;
        offs[b + 1] = run;
        if (c1 > 0) gpos[b + 1] = atomicAdd(&cursor[b + 1], c1);
        run += c1;
        offs[b + 2] = run;
        if (c2 > 0) gpos[b + 2] = atomicAdd(&cursor[b + 2], c2);
        run += c2;
        offs[b + 3] = run;
        if (c3 > 0) gpos[b + 3] = atomicAdd(&cursor[b + 3], c3);
    }
    __syncthreads();

#pragma unroll
    for (int k = 0; k < 16; ++k) {
        if (myb[k] >= 0) {
            int p = offs[myb[k]] + myr[k];
            st[p] = make_int2(myw0[k], __float_as_int(myw1[k]));
            stb[p] = (unsigned short)myb[k];
        }
    }
    __syncthreads();

    for (int i = threadIdx.x; i < tn; i += 256) {
        int b = stb[i];
        int dest = gpos[b] + (i - offs[b]);
        stage2[dest] = st[i];
    }
}

// bin src ids by src-bucket: stage_s[pos] = src_local (byte, 0..127)
__global__ __launch_bounds__(256) void k_binpass_src(
    const int* __restrict__ src, int* __restrict__ cursor, unsigned char* __restrict__ stage_s, int E) {
    __shared__ int cnt[NBUCK_PAD];
    __shared__ int offs[NBUCK_PAD];
    __shared__ int gpos[NBUCK_PAD];
    __shared__ int sc[256];
    __shared__ unsigned char st[TILE];
    __shared__ unsigned short stb[TILE];

    int base = blockIdx.x * TILE;
    int tn = E - base; if (tn > TILE) tn = TILE;

    for (int i = threadIdx.x; i < NBUCK_PAD; i += 256) cnt[i] = 0;
    __syncthreads();

    int myv[16]; int myb[16]; int myr[16];
#pragma unroll
    for (int k = 0; k < 16; ++k) {
        int idx = base + threadIdx.x + k * 256;
        myb[k] = -1;
        if (idx < E) {
            int s = src[idx];
            int b = s >> BK_SHIFT;
            myv[k] = s & (BK_NODES - 1);
            myb[k] = b;
            myr[k] = atomicAdd(&cnt[b], 1);
        }
    }
    __syncthreads();

    int t = threadIdx.x;
    int c0 = cnt[t * 4], c1 = cnt[t * 4 + 1], c2 = cnt[t * 4 + 2], c3 = cnt[t * 4 + 3];
    int tot = c0 + c1 + c2 + c3;
    sc[t] = tot;
    __syncthreads();
#pragma unroll
    for (int off = 1; off < 256; off <<= 1) {
        int v = (t >= off) ? sc[t - off] : 0;
        __syncthreads();
        sc[t] += v;
        __syncthreads();
    }
    int run = sc[t] - tot;
    {
        int b = t * 4;
        offs[b] = run;
        if (c0 > 0) gpos[b] = atomicAdd(&cursor[b], c0);
        run += c0;
        offs[b + 1] = run;
        if (c1 > 0) gpos[b + 1] = atomicAdd(&cursor[b + 1], c1);
        run += c1;
        offs[b + 2] = run;
        if (c2 > 0) gpos[b + 2] = atomicAdd(&cursor[b + 2], c2);
        run += c2;
        offs[b + 3] = run;
        if (c3 > 0) gpos[b + 3] = atomicAdd(&cursor[b + 3], c3);
    }
    __syncthreads();

#pragma unroll
    for (int k = 0; k < 16; ++k) {
        if (myb[k] >= 0) {
            int p = offs[myb[k]] + myr[k];
            st[p] = (unsigned char)myv[k];
            stb[p] = (unsigned short)myb[k];
        }
    }
    __syncthreads();

    for (int i = threadIdx.x; i < tn; i += 256) {
        int b = stb[i];
        int dest = gpos[b] + (i - offs[b]);
        stage_s[dest] = st[i];
    }
}

// per-bucket: count src occurrences -> deg_out -> no[n], xs[n*8+f]=x*no (8-padded)
__global__ __launch_bounds__(256) void k_prep_src(
    const int* __restrict__ base_s, const unsigned char* __restrict__ stage_s, const float* __restrict__ x,
    float* __restrict__ no, float* __restrict__ xs, int N) {
    __shared__ int cnt[BK_NODES];
    int b = blockIdx.x;
    int beg = base_s[b], end = base_s[b + 1];
    if (threadIdx.x < BK_NODES) cnt[threadIdx.x] = 0;
    __syncthreads();
    for (int j = beg + threadIdx.x; j < end; j += 256) atomicAdd(&cnt[stage_s[j]], 1);
    __syncthreads();
    if (threadIdx.x < BK_NODES) {
        int n = (b << BK_SHIFT) + threadIdx.x;
        if (n < N) {
            float nov = rsqrtf(fmaxf((float)cnt[threadIdx.x], 1.0f));
            no[n] = nov;
#pragma unroll
            for (int f = 0; f < 7; ++f) xs[n * 8 + f] = x[n * 7 + f] * nov;
            xs[n * 8 + 7] = 0.f;
        }
    }
}

// per-bucket: count dst -> deg_in -> ni, local scan -> row_ptr, then exact CSR placement
__global__ __launch_bounds__(256) void k_scatter2(
    const int* __restrict__ base_d, const int2* __restrict__ stage2,
    int* __restrict__ row_ptr, float* __restrict__ ni,
    int* __restrict__ csr_src, float* __restrict__ csr_w, int N) {
    __shared__ int cnt[BK_NODES];
    __shared__ int scn[BK_NODES];
    __shared__ int cur[BK_NODES];
    int b = blockIdx.x;
    int beg = base_d[b], end = base_d[b + 1];
    if (threadIdx.x < BK_NODES) cnt[threadIdx.x] = 0;
    __syncthreads();
    for (int j = beg + threadIdx.x; j < end; j += 256) atomicAdd(&cnt[stage2[j].x >> 17], 1);
    __syncthreads();
    int v = (threadIdx.x < BK_NODES) ? cnt[threadIdx.x] : 0;
    if (threadIdx.x < BK_NODES) scn[threadIdx.x] = v;
    __syncthreads();
#pragma unroll
    for (int off = 1; off < BK_NODES; off <<= 1) {
        int t = (threadIdx.x < BK_NODES && threadIdx.x >= off) ? scn[threadIdx.x - off] : 0;
        __syncthreads();
        if (threadIdx.x < BK_NODES) scn[threadIdx.x] += t;
        __syncthreads();
    }
    if (threadIdx.x < BK_NODES) {
        int ex = scn[threadIdx.x] - v;
        cur[threadIdx.x] = beg + ex;
        int n = (b << BK_SHIFT) + threadIdx.x;
        if (n < N) {
            row_ptr[n] = beg + ex;
            ni[n] = rsqrtf(fmaxf((float)v, 1.0f));
        }
    }
    __syncthreads();
    for (int j = beg + threadIdx.x; j < end; j += 256) {
        int2 t = stage2[j];
        int dl = t.x >> 17;
        int pos = atomicAdd(&cur[dl], 1);
        csr_src[pos] = t.x & SRC_MASK;
        csr_w[pos] = __int_as_float(t.y);
    }
}

// ---------------- fused layers (per-node shfl-walk gather, 4-way ILP) ----------------

__global__ __launch_bounds__(256) void k_layer1(
    const int* __restrict__ rp, const int* __restrict__ csr_src, const float* __restrict__ csr_w,
    const float* __restrict__ xs, const float* __restrict__ ni, const float* __restrict__ no,
    const float* __restrict__ W1, const float* __restrict__ b1, float* __restrict__ h1s, int N) {
    __shared__ float sW[7 * 32];
    __shared__ float sb[32];
    __shared__ float sh7[32][8];
    for (int i = threadIdx.x; i < 7 * 32; i += 256) sW[i] = W1[i];
    if (threadIdx.x < 32) sb[threadIdx.x] = b1[threadIdx.x];

    int g = threadIdx.x >> 3, lane = threadIdx.x & 7;
    int node = blockIdx.x * 32 + g;
    float acc = 0.f;
    if (node < N) {
        int beg = rp[node], end = rp[node + 1];
        for (int j0 = beg; j0 < end; j0 += 8) {
            int ms = 0; float mw = 0.f;
            if (j0 + lane < end) {
                ms = csr_src[j0 + lane];
                mw = csr_w[j0 + lane];
            }
            int m = end - j0; if (m > 8) m = 8;
            float a0 = 0.f, a1 = 0.f, a2 = 0.f, a3 = 0.f;
            int k = 0;
            for (; k + 4 <= m; k += 4) {
                int s0 = __shfl(ms, k, 8);     float w0 = __shfl(mw, k, 8);
                int s1 = __shfl(ms, k + 1, 8); float w1 = __shfl(mw, k + 1, 8);
                int s2 = __shfl(ms, k + 2, 8); float w2 = __shfl(mw, k + 2, 8);
                int s3 = __shfl(ms, k + 3, 8); float w3 = __shfl(mw, k + 3, 8);
                a0 += xs[s0 * 8 + lane] * w0;
                a1 += xs[s1 * 8 + lane] * w1;
                a2 += xs[s2 * 8 + lane] * w2;
                a3 += xs[s3 * 8 + lane] * w3;
            }
            for (; k < m; ++k) {
                int s = __shfl(ms, k, 8);
                float w = __shfl(mw, k, 8);
                a0 += xs[s * 8 + lane] * w;
            }
            acc += (a0 + a1) + (a2 + a3);
        }
        acc *= ni[node];
    }
    sh7[g][lane] = acc;
    __syncthreads();

    int g2 = threadIdx.x >> 5, l32 = threadIdx.x & 31;
#pragma unroll
    for (int t = 0; t < 4; ++t) {
        int nl = t * 8 + g2;
        int node2 = blockIdx.x * 32 + nl;
        if (node2 < N) {
            float o = sb[l32];
#pragma unroll
            for (int k = 0; k < 7; ++k) o += sh7[nl][k] * sW[k * 32 + l32];
            h1s[node2 * 32 + l32] = fmaxf(o, 0.f) * no[node2];
        }
    }
}

__global__ __launch_bounds__(256) void k_layer32(
    const int* __restrict__ rp, const int* __restrict__ csr_src, const float* __restrict__ h_in,
    const float* __restrict__ ni, const float* __restrict__ no, const float* __restrict__ W,
    const float* __restrict__ b, float* __restrict__ h_out, int N) {
    __shared__ float sW[32 * 32];
    __shared__ float sb[32];
    __shared__ float shv[8][32];
    for (int i = threadIdx.x; i < 1024; i += 256) sW[i] = W[i];
    if (threadIdx.x < 32) sb[threadIdx.x] = b[threadIdx.x];

    int g = threadIdx.x >> 5, lane = threadIdx.x & 31;
    int node = blockIdx.x * 8 + g;
    float acc = 0.f;
    if (node < N) {
        int beg = rp[node], end = rp[node + 1];
        for (int j0 = beg; j0 < end; j0 += 32) {
            int ms = (j0 + lane < end) ? csr_src[j0 + lane] : 0;
            int m = end - j0; if (m > 32) m = 32;
            float a0 = 0.f, a1 = 0.f, a2 = 0.f, a3 = 0.f;
            int k = 0;
            for (; k + 4 <= m; k += 4) {
                int s0 = __shfl(ms, k, 32);
                int s1 = __shfl(ms, k + 1, 32);
                int s2 = __shfl(ms, k + 2, 32);
                int s3 = __shfl(ms, k + 3, 32);
                a0 += h_in[s0 * 32 + lane];
                a1 += h_in[s1 * 32 + lane];
                a2 += h_in[s2 * 32 + lane];
                a3 += h_in[s3 * 32 + lane];
            }
            for (; k < m; ++k) {
                int s = __shfl(ms, k, 32);
                a0 += h_in[s * 32 + lane];
            }
            acc += (a0 + a1) + (a2 + a3);
        }
        acc *= ni[node];
    }
    shv[g][lane] = acc;
    __syncthreads();
    if (node < N) {
        float o = sb[lane];
#pragma unroll
        for (int k = 0; k < 32; ++k) o += shv[g][k] * sW[k * 32 + lane];
        h_out[node * 32 + lane] = fmaxf(o, 0.f) * no[node];
    }
}

__global__ __launch_bounds__(256) void k_layer34(
    const int* __restrict__ rp, const int* __restrict__ csr_src, const float* __restrict__ h_in,
    const float* __restrict__ ni, const float* __restrict__ no, const float* __restrict__ W3,
    const float* __restrict__ b3, const float* __restrict__ W4, float2* __restrict__ h4pre, int N) {
    __shared__ float sW[32 * 32];
    __shared__ float sb[32];
    __shared__ float sW4[64];
    __shared__ float shv[8][32];
    for (int i = threadIdx.x; i < 1024; i += 256) sW[i] = W3[i];
    if (threadIdx.x < 32) sb[threadIdx.x] = b3[threadIdx.x];
    if (threadIdx.x < 64) sW4[threadIdx.x] = W4[threadIdx.x];

    int g = threadIdx.x >> 5, lane = threadIdx.x & 31;
    int node = blockIdx.x * 8 + g;
    float acc = 0.f;
    if (node < N) {
        int beg = rp[node], end = rp[node + 1];
        for (int j0 = beg; j0 < end; j0 += 32) {
            int ms = (j0 + lane < end) ? csr_src[j0 + lane] : 0;
            int m = end - j0; if (m > 32) m = 32;
            float a0 = 0.f, a1 = 0.f, a2 = 0.f, a3 = 0.f;
            int k = 0;
            for (; k + 4 <= m; k += 4) {
                int s0 = __shfl(ms, k, 32);
                int s1 = __shfl(ms, k + 1, 32);
                int s2 = __shfl(ms, k + 2, 32);
                int s3 = __shfl(ms, k + 3, 32);
                a0 += h_in[s0 * 32 + lane];
                a1 += h_in[s1 * 32 + lane];
                a2 += h_in[s2 * 32 + lane];
                a3 += h_in[s3 * 32 + lane];
            }
            for (; k < m; ++k) {
                int s = __shfl(ms, k, 32);
                a0 += h_in[s * 32 + lane];
            }
            acc += (a0 + a1) + (a2 + a3);
        }
        acc *= ni[node];
    }
    shv[g][lane] = acc;
    __syncthreads();
    if (node < N) {
        float o = sb[lane];
#pragma unroll
        for (int k = 0; k < 32; ++k) o += shv[g][k] * sW[k * 32 + lane];
        float t = fmaxf(o, 0.f) * no[node];
        float px = t * sW4[lane * 2 + 0];
        float py = t * sW4[lane * 2 + 1];
#pragma unroll
        for (int off = 16; off; off >>= 1) {
            px += __shfl_xor(px, off, 32);
            py += __shfl_xor(py, off, 32);
        }
        if (lane == 0) h4pre[node] = make_float2(px, py);
    }
}

__global__ void k_agg4(const int* __restrict__ rp, const int* __restrict__ csr_src,
                       const float2* __restrict__ h4pre, const float* __restrict__ ni,
                       float2* __restrict__ agg2, int N) {
    int n = blockIdx.x * blockDim.x + threadIdx.x;
    if (n >= N) return;
    int beg = rp[n], end = rp[n + 1];
    float ax0 = 0.f, ay0 = 0.f, ax1 = 0.f, ay1 = 0.f;
    int j = beg;
    for (; j + 2 <= end; j += 2) {
        int s0 = csr_src[j], s1 = csr_src[j + 1];
        float2 v0 = h4pre[s0];
        float2 v1 = h4pre[s1];
        ax0 += v0.x; ay0 += v0.y;
        ax1 += v1.x; ay1 += v1.y;
    }
    if (j < end) {
        float2 v = h4pre[csr_src[j]];
        ax0 += v.x; ay0 += v.y;
    }
    float w = ni[n];
    agg2[n] = make_float2((ax0 + ax1) * w, (ay0 + ay1) * w);
}

__global__ void k_pool(const float2* __restrict__ agg2, const int* __restrict__ gid,
                       const float* __restrict__ b4, float* __restrict__ out, int N) {
    int g = blockIdx.x;
    int lo = 0, hi = N;
    while (lo < hi) { int m = (lo + hi) >> 1; if (gid[m] < g) lo = m + 1; else hi = m; }
    int start = lo;
    int lo2 = start, hi2 = N;
    while (lo2 < hi2) { int m = (lo2 + hi2) >> 1; if (gid[m] < g + 1) lo2 = m + 1; else hi2 = m; }
    int end = lo2;
    float sx = 0.f, sy = 0.f;
    for (int n = start + threadIdx.x; n < end; n += 64) {
        float2 v = agg2[n];
        sx += v.x;
        sy += v.y;
    }
#pragma unroll
    for (int off = 32; off; off >>= 1) {
        sx += __shfl_down(sx, off, 64);
        sy += __shfl_down(sy, off, 64);
    }
    if (threadIdx.x == 0) {
        int cnt = end - start;
        float inv = 1.0f / fmaxf((float)cnt, 1.0f);
        float scale = (float)cnt * inv;  // 0 if empty, else 1
        out[g * 2 + 0] = sx * inv + b4[0] * scale;
        out[g * 2 + 1] = sy * inv + b4[1] * scale;
    }
}

// ---------------- launch ----------------

extern "C" void kernel_launch(void* const* d_in, const int* in_sizes, int n_in,
                              void* d_out, int out_size, void* d_ws, size_t ws_size,
                              hipStream_t stream) {
    const float* x   = (const float*)d_in[0];
    const float* e   = (const float*)d_in[1];
    const float* W1  = (const float*)d_in[2];
    const float* b1  = (const float*)d_in[3];
    const float* W2  = (const float*)d_in[4];
    const float* b2  = (const float*)d_in[5];
    const float* W3  = (const float*)d_in[6];
    const float* b3  = (const float*)d_in[7];
    const float* W4  = (const float*)d_in[8];
    const float* b4  = (const float*)d_in[9];
    const int*   src = (const int*)d_in[10];
    const int*   dst = (const int*)d_in[11];
    const int*   gid = (const int*)d_in[12];
    float* out = (float*)d_out;

    const int N = NN, E = NE;
    const int G = out_size / 2;

    const size_t TC = ((size_t)NTILES * NBUCK + 3) & ~(size_t)3;  // 477,804

    int* ws_i = (int*)d_ws;
    int* tc_d     = ws_i;                         // TC
    int* tc_s     = ws_i + TC;                    // TC
    int* tot_d    = ws_i + 2 * TC;                // 1024
    int* tot_s    = ws_i + 2 * TC + 1024;         // 1024
    int* base_d   = ws_i + 2 * TC + 2048;         // 1024 (need 783)
    int* base_s   = ws_i + 2 * TC + 3072;         // 1024
    int* cursor_d = ws_i + 2 * TC + 4096;         // 1024
    int* cursor_s = ws_i + 2 * TC + 5120;         // 1024
    int* row_ptr  = ws_i + 2 * TC + 6144;         // N+4
    int* csr_src  = ws_i + 2 * TC + 6144 + (size_t)N + 4;       // E
    float* csr_w  = (float*)(ws_i + 2 * TC + 6144 + (size_t)N + 4 + (size_t)E); // E
    unsigned char* stage_s = (unsigned char*)csr_w;  // alias: dead before csr_w written

    float* fbase = (float*)(ws_i + 2 * TC + 6144 + (size_t)N + 4 + 2 * (size_t)E);
    float* no_b  = fbase;                          // N
    float* ni_b  = fbase + (size_t)N;              // N
    float* xs    = fbase + (size_t)2 * N;          // 8N
    float* h1s   = fbase + (size_t)10 * N;         // 32N
    float* h2s   = fbase + (size_t)42 * N;         // 32N
    float2* h4pre = (float2*)(fbase + (size_t)74 * N); // 2N
    float2* agg2  = (float2*)(fbase + (size_t)76 * N); // 2N
    // stage2 aliased over h1s/h2s (2E ints = 5M <= 64N = 6.4M; dead before layer1 writes h1s)
    int2* stage2 = (int2*)(fbase + (size_t)10 * N);

    k_tilecnt<<<NTILES, 256, 0, stream>>>(src, dst, tc_d, tc_s, E);
    k_coltot<<<2 * NBUCK, 256, 0, stream>>>(tc_d, tc_s, tot_d, tot_s);
    k_bucket_scan<<<1, 1024, 0, stream>>>(tot_d, tot_s, base_d, base_s, cursor_d, cursor_s, row_ptr, E);
    k_binpass<<<NTILES, 256, 0, stream>>>(src, dst, e, cursor_d, stage2, E);
    k_binpass_src<<<NTILES, 256, 0, stream>>>(src, cursor_s, stage_s, E);
    k_prep_src<<<NBUCK, 256, 0, stream>>>(base_s, stage_s, x, no_b, xs, N);
    k_scatter2<<<NBUCK, 256, 0, stream>>>(base_d, stage2, row_ptr, ni_b, csr_src, csr_w, N);

    k_layer1<<<(N + 31) / 32, 256, 0, stream>>>(row_ptr, csr_src, csr_w, xs, ni_b, no_b, W1, b1, h1s, N);
    k_layer32<<<(N + 7) / 8, 256, 0, stream>>>(row_ptr, csr_src, h1s, ni_b, no_b, W2, b2, h2s, N);
    k_layer34<<<(N + 7) / 8, 256, 0, stream>>>(row_ptr, csr_src, h2s, ni_b, no_b, W3, b3, W4, h4pre, N);
    k_agg4<<<(N + 255) / 256, 256, 0, stream>>>(row_ptr, csr_src, h4pre, ni_b, agg2, N);
    k_pool<<<G, 64, 0, stream>>>(agg2, gid, b4, out, N);
}

// Round 8
// 439.584 us; speedup vs baseline: 3.7417x; 1.1919x over previous
//
#include <hip/hip_runtime.h>

#define NN 100000
#define NE 2500000
#define BK_SHIFT 7
#define BK_NODES 128
#define NBUCK ((NN + BK_NODES - 1) / BK_NODES)   // 782
#define TILE 4096
#define NTILES ((NE + TILE - 1) / TILE)     // 611
#define SRC_MASK 0x1FFFF                    // 17 bits, NN < 131072

// ---------------- CSR build: tile hist -> bucket totals -> scan -> direct-write binning ----------------

// per-tile LDS histograms; flush per-bucket totals via global atomics (6KB target array)
__global__ __launch_bounds__(256) void k_tilecnt2(const int* __restrict__ src,
                                                  const int* __restrict__ dst,
                                                  int* __restrict__ tot_d, int* __restrict__ tot_s,
                                                  int E) {
    __shared__ int cd[NBUCK];
    __shared__ int cs[NBUCK];
    int base = blockIdx.x * TILE;
    for (int i = threadIdx.x; i < NBUCK; i += 256) { cd[i] = 0; cs[i] = 0; }
    __syncthreads();
#pragma unroll
    for (int k = 0; k < 16; ++k) {
        int idx = base + threadIdx.x + k * 256;
        if (idx < E) {
            atomicAdd(&cd[dst[idx] >> BK_SHIFT], 1);
            atomicAdd(&cs[src[idx] >> BK_SHIFT], 1);
        }
    }
    __syncthreads();
    for (int i = threadIdx.x; i < NBUCK; i += 256) {
        int c = cd[i]; if (c) atomicAdd(&tot_d[i], c);
        c = cs[i];     if (c) atomicAdd(&tot_s[i], c);
    }
}

// single-block scan of both bucket-total arrays -> bases + cursor init; row_ptr[N]=E
__global__ __launch_bounds__(1024) void k_bucket_scan(const int* __restrict__ tot_d,
                                                      const int* __restrict__ tot_s,
                                                      int* __restrict__ base_d, int* __restrict__ base_s,
                                                      int* __restrict__ cursor_d, int* __restrict__ cursor_s,
                                                      int* __restrict__ row_ptr, int E) {
    __shared__ int sh[1024];
    int tid = threadIdx.x;
    // dst
    int v = (tid < NBUCK) ? tot_d[tid] : 0;
    sh[tid] = v;
    __syncthreads();
#pragma unroll
    for (int off = 1; off < 1024; off <<= 1) {
        int t = (tid >= off) ? sh[tid - off] : 0;
        __syncthreads();
        sh[tid] += t;
        __syncthreads();
    }
    if (tid < NBUCK) { int ex = sh[tid] - v; base_d[tid] = ex; cursor_d[tid] = ex; }
    if (tid == 0) { base_d[NBUCK] = E; row_ptr[NN] = E; }
    __syncthreads();
    // src
    v = (tid < NBUCK) ? tot_s[tid] : 0;
    sh[tid] = v;
    __syncthreads();
#pragma unroll
    for (int off = 1; off < 1024; off <<= 1) {
        int t = (tid >= off) ? sh[tid - off] : 0;
        __syncthreads();
        sh[tid] += t;
        __syncthreads();
    }
    if (tid < NBUCK) { int ex = sh[tid] - v; base_s[tid] = ex; cursor_s[tid] = ex; }
    if (tid == 0) base_s[NBUCK] = E;
}

// merged binning, direct writes, no staging/scan:
// stage2[gpos_d[bd]+rank_d] = (src | dst_local<<17, w);  stage_s[gpos_s[bs]+rank_s] = src_local
__global__ __launch_bounds__(256) void k_binpass2(
    const int* __restrict__ src, const int* __restrict__ dst, const float* __restrict__ ew,
    int* __restrict__ cursor_d, int* __restrict__ cursor_s,
    int2* __restrict__ stage2, unsigned char* __restrict__ stage_s, int E) {
    __shared__ int cnt_d[NBUCK];
    __shared__ int gpos_d[NBUCK];
    __shared__ int cnt_s[NBUCK];
    __shared__ int gpos_s[NBUCK];

    int base = blockIdx.x * TILE;
    for (int i = threadIdx.x; i < NBUCK; i += 256) { cnt_d[i] = 0; cnt_s[i] = 0; }
    __syncthreads();

    int w0[16]; float w1[16]; int pd[16]; int rs[16];
#pragma unroll
    for (int k = 0; k < 16; ++k) {
        int idx = base + threadIdx.x + k * 256;
        pd[k] = -1;
        if (idx < E) {
            int s = src[idx], d = dst[idx];
            w1[k] = ew[idx];
            int bd = d >> BK_SHIFT;
            w0[k] = s | ((d & (BK_NODES - 1)) << 17);
            int rd = atomicAdd(&cnt_d[bd], 1);
            pd[k] = bd | (rd << 10);
            rs[k] = atomicAdd(&cnt_s[s >> BK_SHIFT], 1);
        }
    }
    __syncthreads();

    // one global allocation per nonzero bucket per side
    for (int i = threadIdx.x; i < NBUCK; i += 256) {
        int c = cnt_d[i]; if (c) gpos_d[i] = atomicAdd(&cursor_d[i], c);
        c = cnt_s[i];     if (c) gpos_s[i] = atomicAdd(&cursor_s[i], c);
    }
    __syncthreads();

#pragma unroll
    for (int k = 0; k < 16; ++k) {
        if (pd[k] >= 0) {
            int bd = pd[k] & 1023, rd = pd[k] >> 10;
            stage2[gpos_d[bd] + rd] = make_int2(w0[k], __float_as_int(w1[k]));
            int s = w0[k] & SRC_MASK;
            stage_s[gpos_s[s >> BK_SHIFT] + rs[k]] = (unsigned char)(s & (BK_NODES - 1));
        }
    }
}

// per-bucket: count src occurrences -> deg_out -> no[n], xs[n*8+f]=x*no (8-padded)
__global__ __launch_bounds__(256) void k_prep_src(
    const int* __restrict__ base_s, const unsigned char* __restrict__ stage_s, const float* __restrict__ x,
    float* __restrict__ no, float* __restrict__ xs, int N) {
    __shared__ int cnt[BK_NODES];
    int b = blockIdx.x;
    int beg = base_s[b], end = base_s[b + 1];
    if (threadIdx.x < BK_NODES) cnt[threadIdx.x] = 0;
    __syncthreads();
    for (int j = beg + threadIdx.x; j < end; j += 256) atomicAdd(&cnt[stage_s[j]], 1);
    __syncthreads();
    if (threadIdx.x < BK_NODES) {
        int n = (b << BK_SHIFT) + threadIdx.x;
        if (n < N) {
            float nov = rsqrtf(fmaxf((float)cnt[threadIdx.x], 1.0f));
            no[n] = nov;
#pragma unroll
            for (int f = 0; f < 7; ++f) xs[n * 8 + f] = x[n * 7 + f] * nov;
            xs[n * 8 + 7] = 0.f;
        }
    }
}

// per-bucket: count dst -> deg_in -> ni, local scan -> row_ptr, then exact CSR placement
__global__ __launch_bounds__(256) void k_scatter2(
    const int* __restrict__ base_d, const int2* __restrict__ stage2,
    int* __restrict__ row_ptr, float* __restrict__ ni,
    int* __restrict__ csr_src, float* __restrict__ csr_w, int N) {
    __shared__ int cnt[BK_NODES];
    __shared__ int scn[BK_NODES];
    __shared__ int cur[BK_NODES];
    int b = blockIdx.x;
    int beg = base_d[b], end = base_d[b + 1];
    if (threadIdx.x < BK_NODES) cnt[threadIdx.x] = 0;
    __syncthreads();
    for (int j = beg + threadIdx.x; j < end; j += 256) atomicAdd(&cnt[stage2[j].x >> 17], 1);
    __syncthreads();
    int v = (threadIdx.x < BK_NODES) ? cnt[threadIdx.x] : 0;
    if (threadIdx.x < BK_NODES) scn[threadIdx.x] = v;
    __syncthreads();
#pragma unroll
    for (int off = 1; off < BK_NODES; off <<= 1) {
        int t = (threadIdx.x < BK_NODES && threadIdx.x >= off) ? scn[threadIdx.x - off] : 0;
        __syncthreads();
        if (threadIdx.x < BK_NODES) scn[threadIdx.x] += t;
        __syncthreads();
    }
    if (threadIdx.x < BK_NODES) {
        int ex = scn[threadIdx.x] - v;
        cur[threadIdx.x] = beg + ex;
        int n = (b << BK_SHIFT) + threadIdx.x;
        if (n < N) {
            row_ptr[n] = beg + ex;
            ni[n] = rsqrtf(fmaxf((float)v, 1.0f));
        }
    }
    __syncthreads();
    for (int j = beg + threadIdx.x; j < end; j += 256) {
        int2 t = stage2[j];
        int dl = t.x >> 17;
        int pos = atomicAdd(&cur[dl], 1);
        csr_src[pos] = t.x & SRC_MASK;
        csr_w[pos] = __int_as_float(t.y);
    }
}

// ---------------- fused layers (per-node shfl-walk gather, 4-way ILP) ----------------

__global__ __launch_bounds__(256) void k_layer1(
    const int* __restrict__ rp, const int* __restrict__ csr_src, const float* __restrict__ csr_w,
    const float* __restrict__ xs, const float* __restrict__ ni, const float* __restrict__ no,
    const float* __restrict__ W1, const float* __restrict__ b1, float* __restrict__ h1s, int N) {
    __shared__ float sW[7 * 32];
    __shared__ float sb[32];
    __shared__ float sh7[32][8];
    for (int i = threadIdx.x; i < 7 * 32; i += 256) sW[i] = W1[i];
    if (threadIdx.x < 32) sb[threadIdx.x] = b1[threadIdx.x];

    int g = threadIdx.x >> 3, lane = threadIdx.x & 7;
    int node = blockIdx.x * 32 + g;
    float acc = 0.f;
    if (node < N) {
        int beg = rp[node], end = rp[node + 1];
        for (int j0 = beg; j0 < end; j0 += 8) {
            int ms = 0; float mw = 0.f;
            if (j0 + lane < end) {
                ms = csr_src[j0 + lane];
                mw = csr_w[j0 + lane];
            }
            int m = end - j0; if (m > 8) m = 8;
            float a0 = 0.f, a1 = 0.f, a2 = 0.f, a3 = 0.f;
            int k = 0;
            for (; k + 4 <= m; k += 4) {
                int s0 = __shfl(ms, k, 8);     float w0 = __shfl(mw, k, 8);
                int s1 = __shfl(ms, k + 1, 8); float w1 = __shfl(mw, k + 1, 8);
                int s2 = __shfl(ms, k + 2, 8); float w2 = __shfl(mw, k + 2, 8);
                int s3 = __shfl(ms, k + 3, 8); float w3 = __shfl(mw, k + 3, 8);
                a0 += xs[s0 * 8 + lane] * w0;
                a1 += xs[s1 * 8 + lane] * w1;
                a2 += xs[s2 * 8 + lane] * w2;
                a3 += xs[s3 * 8 + lane] * w3;
            }
            for (; k < m; ++k) {
                int s = __shfl(ms, k, 8);
                float w = __shfl(mw, k, 8);
                a0 += xs[s * 8 + lane] * w;
            }
            acc += (a0 + a1) + (a2 + a3);
        }
        acc *= ni[node];
    }
    sh7[g][lane] = acc;
    __syncthreads();

    int g2 = threadIdx.x >> 5, l32 = threadIdx.x & 31;
#pragma unroll
    for (int t = 0; t < 4; ++t) {
        int nl = t * 8 + g2;
        int node2 = blockIdx.x * 32 + nl;
        if (node2 < N) {
            float o = sb[l32];
#pragma unroll
            for (int k = 0; k < 7; ++k) o += sh7[nl][k] * sW[k * 32 + l32];
            h1s[node2 * 32 + l32] = fmaxf(o, 0.f) * no[node2];
        }
    }
}

__global__ __launch_bounds__(256) void k_layer32(
    const int* __restrict__ rp, const int* __restrict__ csr_src, const float* __restrict__ h_in,
    const float* __restrict__ ni, const float* __restrict__ no, const float* __restrict__ W,
    const float* __restrict__ b, float* __restrict__ h_out, int N) {
    __shared__ float sW[32 * 32];
    __shared__ float sb[32];
    __shared__ float shv[8][32];
    for (int i = threadIdx.x; i < 1024; i += 256) sW[i] = W[i];
    if (threadIdx.x < 32) sb[threadIdx.x] = b[threadIdx.x];

    int g = threadIdx.x >> 5, lane = threadIdx.x & 31;
    int node = blockIdx.x * 8 + g;
    float acc = 0.f;
    if (node < N) {
        int beg = rp[node], end = rp[node + 1];
        for (int j0 = beg; j0 < end; j0 += 32) {
            int ms = (j0 + lane < end) ? csr_src[j0 + lane] : 0;
            int m = end - j0; if (m > 32) m = 32;
            float a0 = 0.f, a1 = 0.f, a2 = 0.f, a3 = 0.f;
            int k = 0;
            for (; k + 4 <= m; k += 4) {
                int s0 = __shfl(ms, k, 32);
                int s1 = __shfl(ms, k + 1, 32);
                int s2 = __shfl(ms, k + 2, 32);
                int s3 = __shfl(ms, k + 3, 32);
                a0 += h_in[s0 * 32 + lane];
                a1 += h_in[s1 * 32 + lane];
                a2 += h_in[s2 * 32 + lane];
                a3 += h_in[s3 * 32 + lane];
            }
            for (; k < m; ++k) {
                int s = __shfl(ms, k, 32);
                a0 += h_in[s * 32 + lane];
            }
            acc += (a0 + a1) + (a2 + a3);
        }
        acc *= ni[node];
    }
    shv[g][lane] = acc;
    __syncthreads();
    if (node < N) {
        float o = sb[lane];
#pragma unroll
        for (int k = 0; k < 32; ++k) o += shv[g][k] * sW[k * 32 + lane];
        h_out[node * 32 + lane] = fmaxf(o, 0.f) * no[node];
    }
}

__global__ __launch_bounds__(256) void k_layer34(
    const int* __restrict__ rp, const int* __restrict__ csr_src, const float* __restrict__ h_in,
    const float* __restrict__ ni, const float* __restrict__ no, const float* __restrict__ W3,
    const float* __restrict__ b3, const float* __restrict__ W4, float2* __restrict__ h4pre, int N) {
    __shared__ float sW[32 * 32];
    __shared__ float sb[32];
    __shared__ float sW4[64];
    __shared__ float shv[8][32];
    for (int i = threadIdx.x; i < 1024; i += 256) sW[i] = W3[i];
    if (threadIdx.x < 32) sb[threadIdx.x] = b3[threadIdx.x];
    if (threadIdx.x < 64) sW4[threadIdx.x] = W4[threadIdx.x];

    int g = threadIdx.x >> 5, lane = threadIdx.x & 31;
    int node = blockIdx.x * 8 + g;
    float acc = 0.f;
    if (node < N) {
        int beg = rp[node], end = rp[node + 1];
        for (int j0 = beg; j0 < end; j0 += 32) {
            int ms = (j0 + lane < end) ? csr_src[j0 + lane] : 0;
            int m = end - j0; if (m > 32) m = 32;
            float a0 = 0.f, a1 = 0.f, a2 = 0.f, a3 = 0.f;
            int k = 0;
            for (; k + 4 <= m; k += 4) {
                int s0 = __shfl(ms, k, 32);
                int s1 = __shfl(ms, k + 1, 32);
                int s2 = __shfl(ms, k + 2, 32);
                int s3 = __shfl(ms, k + 3, 32);
                a0 += h_in[s0 * 32 + lane];
                a1 += h_in[s1 * 32 + lane];
                a2 += h_in[s2 * 32 + lane];
                a3 += h_in[s3 * 32 + lane];
            }
            for (; k < m; ++k) {
                int s = __shfl(ms, k, 32);
                a0 += h_in[s * 32 + lane];
            }
            acc += (a0 + a1) + (a2 + a3);
        }
        acc *= ni[node];
    }
    shv[g][lane] = acc;
    __syncthreads();
    if (node < N) {
        float o = sb[lane];
#pragma unroll
        for (int k = 0; k < 32; ++k) o += shv[g][k] * sW[k * 32 + lane];
        float t = fmaxf(o, 0.f) * no[node];
        float px = t * sW4[lane * 2 + 0];
        float py = t * sW4[lane * 2 + 1];
#pragma unroll
        for (int off = 16; off; off >>= 1) {
            px += __shfl_xor(px, off, 32);
            py += __shfl_xor(py, off, 32);
        }
        if (lane == 0) h4pre[node] = make_float2(px, py);
    }
}

__global__ void k_agg4(const int* __restrict__ rp, const int* __restrict__ csr_src,
                       const float2* __restrict__ h4pre, const float* __restrict__ ni,
                       float2* __restrict__ agg2, int N) {
    int n = blockIdx.x * blockDim.x + threadIdx.x;
    if (n >= N) return;
    int beg = rp[n], end = rp[n + 1];
    float ax0 = 0.f, ay0 = 0.f, ax1 = 0.f, ay1 = 0.f;
    int j = beg;
    for (; j + 2 <= end; j += 2) {
        int s0 = csr_src[j], s1 = csr_src[j + 1];
        float2 v0 = h4pre[s0];
        float2 v1 = h4pre[s1];
        ax0 += v0.x; ay0 += v0.y;
        ax1 += v1.x; ay1 += v1.y;
    }
    if (j < end) {
        float2 v = h4pre[csr_src[j]];
        ax0 += v.x; ay0 += v.y;
    }
    float w = ni[n];
    agg2[n] = make_float2((ax0 + ax1) * w, (ay0 + ay1) * w);
}

__global__ void k_pool(const float2* __restrict__ agg2, const int* __restrict__ gid,
                       const float* __restrict__ b4, float* __restrict__ out, int N) {
    int g = blockIdx.x;
    int lo = 0, hi = N;
    while (lo < hi) { int m = (lo + hi) >> 1; if (gid[m] < g) lo = m + 1; else hi = m; }
    int start = lo;
    int lo2 = start, hi2 = N;
    while (lo2 < hi2) { int m = (lo2 + hi2) >> 1; if (gid[m] < g + 1) lo2 = m + 1; else hi2 = m; }
    int end = lo2;
    float sx = 0.f, sy = 0.f;
    for (int n = start + threadIdx.x; n < end; n += 64) {
        float2 v = agg2[n];
        sx += v.x;
        sy += v.y;
    }
#pragma unroll
    for (int off = 32; off; off >>= 1) {
        sx += __shfl_down(sx, off, 64);
        sy += __shfl_down(sy, off, 64);
    }
    if (threadIdx.x == 0) {
        int cnt = end - start;
        float inv = 1.0f / fmaxf((float)cnt, 1.0f);
        float scale = (float)cnt * inv;  // 0 if empty, else 1
        out[g * 2 + 0] = sx * inv + b4[0] * scale;
        out[g * 2 + 1] = sy * inv + b4[1] * scale;
    }
}

// ---------------- launch ----------------

extern "C" void kernel_launch(void* const* d_in, const int* in_sizes, int n_in,
                              void* d_out, int out_size, void* d_ws, size_t ws_size,
                              hipStream_t stream) {
    const float* x   = (const float*)d_in[0];
    const float* e   = (const float*)d_in[1];
    const float* W1  = (const float*)d_in[2];
    const float* b1  = (const float*)d_in[3];
    const float* W2  = (const float*)d_in[4];
    const float* b2  = (const float*)d_in[5];
    const float* W3  = (const float*)d_in[6];
    const float* b3  = (const float*)d_in[7];
    const float* W4  = (const float*)d_in[8];
    const float* b4  = (const float*)d_in[9];
    const int*   src = (const int*)d_in[10];
    const int*   dst = (const int*)d_in[11];
    const int*   gid = (const int*)d_in[12];
    float* out = (float*)d_out;

    const int N = NN, E = NE;
    const int G = out_size / 2;

    int* ws_i = (int*)d_ws;
    int* tot_d    = ws_i;                         // 1024
    int* tot_s    = ws_i + 1024;                  // 1024
    int* base_d   = ws_i + 2048;                  // 1024 (need 783)
    int* base_s   = ws_i + 3072;                  // 1024
    int* cursor_d = ws_i + 4096;                  // 1024
    int* cursor_s = ws_i + 5120;                  // 1024
    int* row_ptr  = ws_i + 6144;                  // N+4
    int* csr_src  = ws_i + 6144 + (size_t)N + 4;  // E
    float* csr_w  = (float*)(ws_i + 6144 + (size_t)N + 4 + (size_t)E); // E
    unsigned char* stage_s = (unsigned char*)csr_w;  // alias: dead before csr_w written

    float* fbase = (float*)(ws_i + 6144 + (size_t)N + 4 + 2 * (size_t)E);
    float* no_b  = fbase;                          // N
    float* ni_b  = fbase + (size_t)N;              // N
    float* xs    = fbase + (size_t)2 * N;          // 8N
    float* h1s   = fbase + (size_t)10 * N;         // 32N
    float* h2s   = fbase + (size_t)42 * N;         // 32N
    float2* h4pre = (float2*)(fbase + (size_t)74 * N); // 2N
    float2* agg2  = (float2*)(fbase + (size_t)76 * N); // 2N
    // stage2 aliased over h1s/h2s (2E ints = 5M <= 64N = 6.4M; dead before layer1 writes h1s)
    int2* stage2 = (int2*)(fbase + (size_t)10 * N);

    // zero only the bucket-total arrays (8 KB)
    hipMemsetAsync(ws_i, 0, 2048 * sizeof(int), stream);

    k_tilecnt2<<<NTILES, 256, 0, stream>>>(src, dst, tot_d, tot_s, E);
    k_bucket_scan<<<1, 1024, 0, stream>>>(tot_d, tot_s, base_d, base_s, cursor_d, cursor_s, row_ptr, E);
    k_binpass2<<<NTILES, 256, 0, stream>>>(src, dst, e, cursor_d, cursor_s, stage2, stage_s, E);
    k_prep_src<<<NBUCK, 256, 0, stream>>>(base_s, stage_s, x, no_b, xs, N);
    k_scatter2<<<NBUCK, 256, 0, stream>>>(base_d, stage2, row_ptr, ni_b, csr_src, csr_w, N);

    k_layer1<<<(N + 31) / 32, 256, 0, stream>>>(row_ptr, csr_src, csr_w, xs, ni_b, no_b, W1, b1, h1s, N);
    k_layer32<<<(N + 7) / 8, 256, 0, stream>>>(row_ptr, csr_src, h1s, ni_b, no_b, W2, b2, h2s, N);
    k_layer34<<<(N + 7) / 8, 256, 0, stream>>>(row_ptr, csr_src, h2s, ni_b, no_b, W3, b3, W4, h4pre, N);
    k_agg4<<<(N + 255) / 256, 256, 0, stream>>>(row_ptr, csr_src, h4pre, ni_b, agg2, N);
    k_pool<<<G, 64, 0, stream>>>(agg2, gid, b4, out, N);
}